// Round 13
// baseline (358.618 us; speedup 1.0000x reference)
//
#include <hip/hip_runtime.h>
#include <hip/hip_bf16.h>
#include <cstdint>

// Problem constants
#define BB  8
#define CH  64
#define TT  4096
#define KNN 9
#define NEG_INF (-3.402823466e38f)
#define SLOTS 96          // candidate bucket per row (4 quarters x KTH12, 2x slack)
#define SSTR  97          // padded LDS stride (odd -> conflict-free scans)
#define KTH   12          // θ = 12th largest of per-(row,quarter) lane-union

typedef short  s16x8 __attribute__((ext_vector_type(8)));   // 8 bf16 MFMA frag
typedef float  f32x4 __attribute__((ext_vector_type(4)));   // MFMA acc

// Workspace layout (float units) — end 16,060,416 floats = 64.2 MB
constexpr size_t OFF_UB  = 0;                                  // u bf16 [B][9][T][C] ushort
constexpr size_t OFF_QTF = (size_t)BB*KNN*TT*CH/2;             //  9,437,184 qhatT f32 [B][T][C]
constexpr size_t OFF_KTF = OFF_QTF + (size_t)BB*TT*CH;         // 11,534,336 khatT f32
constexpr size_t OFF_QTB = OFF_KTF + (size_t)BB*TT*CH;         // 13,631,488 q bf16 FRAGMENT order
constexpr size_t OFF_KTB = OFF_QTB + (size_t)BB*TT*CH/2;       // 14,680,064 khatT bf16 row-major
constexpr size_t OFF_IDX = OFF_KTB + (size_t)BB*TT*CH/2;       // 15,728,640 idx [B][T][9]
constexpr size_t OFF_CWP = OFF_IDX + (size_t)BB*TT*KNN;        // 16,023,552 cwp [9][64][64]

__device__ __forceinline__ unsigned short f2bf(float f) {
    unsigned u = __float_as_uint(f);
    return (unsigned short)((u + 0x7FFFu + ((u >> 16) & 1u)) >> 16);
}

// value-only ascending top-4 (3 med3 + 1 max); reference params keep SROA.
__device__ __forceinline__ void insert4(float w, float (&s)[4]) {
    s[0] = __builtin_amdgcn_fmed3f(s[0], s[1], w);
    s[1] = __builtin_amdgcn_fmed3f(s[1], s[2], w);
    s[2] = __builtin_amdgcn_fmed3f(s[2], s[3], w);
    s[3] = fmaxf(s[3], w);
}

// θ = KTH-th largest of the union of the quad's 16 top-4 lists (destroys
// lists). Union ⊆ (row, quarter) values ⇒ θ ≤ quarter's KTH-th largest
// ≤ quarter's 9th; any row-global top-9 element in this quarter is within
// the quarter's top-9 ⇒ ≥ θ ⇒ collected. r0-proven statistics.
__device__ __forceinline__ float popTheta4(float (&s)[4], int lane) {
    float theta = NEG_INF;
    #pragma unroll 1
    for (int p = 0; p < KTH; ++p) {
        float h = s[3];
        float m = h;
        m = fmaxf(m, __shfl_xor(m, 1));
        m = fmaxf(m, __shfl_xor(m, 2));
        m = fmaxf(m, __shfl_xor(m, 4));
        m = fmaxf(m, __shfl_xor(m, 8));
        unsigned long long bal = __ballot(h == m);
        unsigned qb = (unsigned)((bal >> (lane & 48)) & 0xFFFFull);
        int owner = __ffs(qb) - 1;
        if ((lane & 15) == owner) {
            s[3] = s[2]; s[2] = s[1]; s[1] = s[0]; s[0] = NEG_INF;
        }
        theta = m;
    }
    return theta;
}

// exact sorted-9 insert, value desc w/ index-asc tiebreak (final sort only)
__device__ __forceinline__ void insert9x(float w, int wi, float (&s)[9], int (&si)[9]) {
    bool c[9];
    #pragma unroll
    for (int k = 0; k < 9; ++k) c[k] = (w > s[k]) || (w == s[k] && wi < si[k]);
    #pragma unroll
    for (int k = 0; k < 8; ++k) si[k] = c[k + 1] ? si[k + 1] : (c[k] ? wi : si[k]);
    si[8] = c[8] ? wi : si[8];
    #pragma unroll
    for (int k = 0; k < 8; ++k) s[k] = c[k + 1] ? s[k + 1] : (c[k] ? w : s[k]);
    s[8] = c[8] ? w : s[8];
}

// ---------------------------------------------------------------------------
// K0: repack conv_w[o][cc*9+kk] -> cwp[kk][cc][o]
// ---------------------------------------------------------------------------
__global__ void repack_cw_kernel(const float* __restrict__ cw, float* __restrict__ cwp) {
    int e = blockIdx.x * blockDim.x + threadIdx.x;
    if (e >= KNN * CH * CH) return;
    int o  = e & 63;
    int cc = (e >> 6) & 63;
    int kk = e >> 12;
    cwp[e] = cw[o * (CH * KNN) + cc * KNN + kk];
}

// ---------------------------------------------------------------------------
// K1: QKV + L2 normalize + u-projection (u bf16) + q/k T-layout fp32 & bf16.
//     q bf16 written in MFMA B-FRAGMENT ORDER (r9 win: 1KB contiguous loads).
// ---------------------------------------------------------------------------
__global__ __launch_bounds__(256) void qkvu_kernel(
        const float* __restrict__ x,
        const float* __restrict__ Wq, const float* __restrict__ Wk, const float* __restrict__ Wv,
        const float* __restrict__ cwp,
        float* __restrict__ qtf, float* __restrict__ ktf,
        unsigned short* __restrict__ qtb, unsigned short* __restrict__ ktb,
        unsigned short* __restrict__ ub) {
    __shared__ __align__(16) float xs[CH * 64];
    __shared__ __align__(16) float vs[CH * 64];
    __shared__ __align__(16) float wl[CH * 64];
    __shared__ float pq[4 * 64], pk[4 * 64];

    const int b   = blockIdx.x >> 6;
    const int tb  = blockIdx.x & 63;
    const int tid = threadIdx.x;

    const float* xb = x + ((size_t)b * CH) * TT + tb * 64;
    #pragma unroll
    for (int m = 0; m < 16; ++m) {
        int l = tid + 256 * m;
        xs[l] = xb[(size_t)(l >> 6) * TT + (l & 63)];
    }
    __syncthreads();

    const int t = tid & 63;
    const int g = __builtin_amdgcn_readfirstlane(tid >> 6);
    const int d0 = g * 16;

    float qa[16], ka[16], va[16];
    #pragma unroll
    for (int dd = 0; dd < 16; ++dd) { qa[dd] = 0.f; ka[dd] = 0.f; va[dd] = 0.f; }

    #pragma unroll 4
    for (int c = 0; c < CH; ++c) {
        float xv = xs[c * 64 + t];
        #pragma unroll
        for (int dd = 0; dd < 16; ++dd) {
            qa[dd] = fmaf(Wq[(d0 + dd) * CH + c], xv, qa[dd]);
            ka[dd] = fmaf(Wk[(d0 + dd) * CH + c], xv, ka[dd]);
            va[dd] = fmaf(Wv[(d0 + dd) * CH + c], xv, va[dd]);
        }
    }

    float sq = 0.f, sk = 0.f;
    #pragma unroll
    for (int dd = 0; dd < 16; ++dd) { sq = fmaf(qa[dd], qa[dd], sq); sk = fmaf(ka[dd], ka[dd], sk); }
    pq[g * 64 + t] = sq;
    pk[g * 64 + t] = sk;
    __syncthreads();

    const float nq = sqrtf(pq[t] + pq[64 + t] + pq[128 + t] + pq[192 + t]);
    const float nk = sqrtf(pk[t] + pk[64 + t] + pk[128 + t] + pk[192 + t]);
    const float isq = 1.0f / fmaxf(nq, 1e-12f);
    const float isk = 1.0f / fmaxf(nk, 1e-12f);

    const size_t tg = (size_t)tb * 64 + t;
    float qn[16], kn[16];
    #pragma unroll
    for (int dd = 0; dd < 16; ++dd) {
        qn[dd] = qa[dd] * isq;
        kn[dd] = ka[dd] * isk;
        vs[(d0 + dd) * 64 + t] = va[dd];
    }
    float* qf = qtf + ((size_t)b * TT + tg) * CH + d0;
    float* kf = ktf + ((size_t)b * TT + tg) * CH + d0;
    #pragma unroll
    for (int p = 0; p < 4; ++p) {
        *(float4*)&qf[p * 4] = make_float4(qn[p*4], qn[p*4+1], qn[p*4+2], qn[p*4+3]);
        *(float4*)&kf[p * 4] = make_float4(kn[p*4], kn[p*4+1], kn[p*4+2], kn[p*4+3]);
    }
    // k bf16: row-major (A-fragments are only 4 loads/kernel in sim)
    unsigned* kh = (unsigned*)(ktb + ((size_t)b * TT + tg) * CH + d0);
    #pragma unroll
    for (int p = 0; p < 8; ++p)
        kh[p] = (unsigned)f2bf(kn[2*p]) | ((unsigned)f2bf(kn[2*p+1]) << 16);

    // q bf16: FRAGMENT order (see r9 comment)
    {
        const int j0   = (int)(tg >> 4);
        const int l15q = (int)tg & 15;
        const int ks   = g >> 1;
        const int q0   = (g & 1) * 2;
        #pragma unroll
        for (int h = 0; h < 2; ++h) {
            unsigned w0 = (unsigned)f2bf(qn[h*8+0]) | ((unsigned)f2bf(qn[h*8+1]) << 16);
            unsigned w1 = (unsigned)f2bf(qn[h*8+2]) | ((unsigned)f2bf(qn[h*8+3]) << 16);
            unsigned w2 = (unsigned)f2bf(qn[h*8+4]) | ((unsigned)f2bf(qn[h*8+5]) << 16);
            unsigned w3 = (unsigned)f2bf(qn[h*8+6]) | ((unsigned)f2bf(qn[h*8+7]) << 16);
            unsigned short* dst = qtb +
                ((((size_t)b * 256 + j0) * 2 + ks) * 64 + ((q0 + h) * 16 + l15q)) * 8;
            *(uint4*)dst = make_uint4(w0, w1, w2, w3);
        }
    }
    __syncthreads();

    const int to = tid & 15;
    const int tt = tid >> 4;
    for (int kk = 0; kk < KNN; ++kk) {
        #pragma unroll
        for (int m = 0; m < 16; ++m) {
            int l = tid + 256 * m;
            wl[l] = cwp[kk * (CH * CH) + l];
        }
        __syncthreads();
        float acc[4][4];
        #pragma unroll
        for (int i = 0; i < 4; ++i)
            #pragma unroll
            for (int j = 0; j < 4; ++j) acc[i][j] = 0.f;

        #pragma unroll 8
        for (int cc = 0; cc < CH; ++cc) {
            float4 wv = *(const float4*)&wl[cc * 64 + 4 * to];
            float4 vv = *(const float4*)&vs[cc * 64 + 4 * tt];
            const float wj[4] = {wv.x, wv.y, wv.z, wv.w};
            const float vi[4] = {vv.x, vv.y, vv.z, vv.w};
            #pragma unroll
            for (int i = 0; i < 4; ++i)
                #pragma unroll
                for (int j = 0; j < 4; ++j) acc[i][j] = fmaf(vi[i], wj[j], acc[i][j]);
        }
        #pragma unroll
        for (int i = 0; i < 4; ++i) {
            size_t row = (size_t)(b * KNN + kk) * TT + tb * 64 + 4 * tt + i;
            unsigned w0 = (unsigned)f2bf(acc[i][0]) | ((unsigned)f2bf(acc[i][1]) << 16);
            unsigned w1 = (unsigned)f2bf(acc[i][2]) | ((unsigned)f2bf(acc[i][3]) << 16);
            *(uint2*)&ub[row * CH + 4 * to] = make_uint2(w0, w1);
        }
        __syncthreads();
    }
}

// ---------------------------------------------------------------------------
// K2: BARRIER-FREE bf16-MFMA sim + top-4 prefilter + θ-collect + exact rescore
//     Round-13: r12's grid-1024 tiling (32-row blocks, 4 waves, wave wq owns
//     all 32 rows x col-quarter) with *** __launch_bounds__(256, 2) *** —
//     r9's proven allocator regime. Root cause of r10-r12 spills: the body's
//     true footprint is ~144 regs (80 VGPR + 64 acc in the unified file);
//     any bound requesting 4 waves/SIMD caps the budget at 128 < 144 ->
//     forced spill. At cap 256 the allocator emits the clean 144; the HW
//     then fits floor(512/144) = 3 waves/SIMD, and grid 1024 (4 blocks/CU
//     available) lets it reach them: occupancy 2 -> 3 waves/SIMD (+50% TLP)
//     with zero register-pressure change. Per-CU work identical to r9.
// ---------------------------------------------------------------------------
__global__ __launch_bounds__(256, 2) void sim_topk_kernel(
        const unsigned short* __restrict__ qtb, const unsigned short* __restrict__ ktb,
        const float* __restrict__ qtf, const float* __restrict__ ktf,
        int* __restrict__ idxout) {
    __shared__ int   cnt[32];
    __shared__ int   bkt[32 * SSTR];
    __shared__ float wbf[32 * SSTR];

    const int b    = blockIdx.x & 7;
    const int ib   = blockIdx.x >> 3;      // 0..127 (32-row tile)
    const int tid  = threadIdx.x;
    const int lane = tid & 63;
    const int wq   = __builtin_amdgcn_readfirstlane(tid >> 6);  // wave -> col quarter
    const int quad = lane >> 4;
    const int l15  = lane & 15;

    if (tid < 32) cnt[tid] = 0;
    __syncthreads();

    // k A-fragments: ALL 32 rows. row = rt*16 + l15, k-chunk = quad*8 + ks*32
    const unsigned short* kb = ktb + ((size_t)b * TT + ib * 32) * CH;
    s16x8 ka[2][2];
    #pragma unroll
    for (int rt = 0; rt < 2; ++rt)
        #pragma unroll
        for (int ks = 0; ks < 2; ++ks)
            ka[rt][ks] = *(const s16x8*)(kb + (size_t)(rt * 16 + l15) * CH + ks * 32 + quad * 8);

    // fragment-order q base for this batch & col-quarter:
    // frag[(b*256 + j0)*2 + ks][lane]*8, j0 = wq*64 + jt*8 + jj
    const unsigned short* qfb = qtb + (((size_t)b * 256 + (size_t)wq * 64) * 2) * 512
                                + (size_t)lane * 8;

    float s[2][4][4];
    #pragma unroll
    for (int rt = 0; rt < 2; ++rt)
        #pragma unroll
        for (int rg = 0; rg < 4; ++rg)
            #pragma unroll
            for (int k = 0; k < 4; ++k) s[rt][rg][k] = NEG_INF;

    // ------------------ PASS A: values-only top-4 (no barriers) ------------
    for (int jt = 0; jt < 8; ++jt) {
        const unsigned short* qrow = qfb + (size_t)(jt * 8) * 1024;  // j0 step=2*512
        s16x8 qf[8][2];
        #pragma unroll
        for (int jj = 0; jj < 8; ++jj)
            #pragma unroll
            for (int ks = 0; ks < 2; ++ks)
                qf[jj][ks] = *(const s16x8*)(qrow + (size_t)(jj * 2 + ks) * 512);

        f32x4 acc[2][8];
        #pragma unroll
        for (int rt = 0; rt < 2; ++rt)
            #pragma unroll
            for (int jj = 0; jj < 8; ++jj) acc[rt][jj] = (f32x4){0.f, 0.f, 0.f, 0.f};
        #pragma unroll
        for (int ks = 0; ks < 2; ++ks)
            #pragma unroll
            for (int rt = 0; rt < 2; ++rt)
                #pragma unroll
                for (int jj = 0; jj < 8; ++jj)
                    acc[rt][jj] = __builtin_amdgcn_mfma_f32_16x16x32_bf16(ka[rt][ks], qf[jj][ks], acc[rt][jj], 0, 0, 0);

        #pragma unroll
        for (int rt = 0; rt < 2; ++rt)
            #pragma unroll
            for (int jj = 0; jj < 8; ++jj) {
                insert4(acc[rt][jj][0], s[rt][0]);
                insert4(acc[rt][jj][1], s[rt][1]);
                insert4(acc[rt][jj][2], s[rt][2]);
                insert4(acc[rt][jj][3], s[rt][3]);
            }
    }

    // per-(row, quarter) θ — valid per quarter; no cross-wave merge needed
    float th[2][4];
    #pragma unroll
    for (int rt = 0; rt < 2; ++rt) {
        th[rt][0] = popTheta4(s[rt][0], lane);
        th[rt][1] = popTheta4(s[rt][1], lane);
        th[rt][2] = popTheta4(s[rt][2], lane);
        th[rt][3] = popTheta4(s[rt][3], lane);
    }

    // ------------------ PASS B: recompute (bitwise-identical) + collect ----
    for (int jt = 0; jt < 8; ++jt) {
        const unsigned short* qrow = qfb + (size_t)(jt * 8) * 1024;
        s16x8 qf[8][2];
        #pragma unroll
        for (int jj = 0; jj < 8; ++jj)
            #pragma unroll
            for (int ks = 0; ks < 2; ++ks)
                qf[jj][ks] = *(const s16x8*)(qrow + (size_t)(jj * 2 + ks) * 512);

        f32x4 acc[2][8];
        #pragma unroll
        for (int rt = 0; rt < 2; ++rt)
            #pragma unroll
            for (int jj = 0; jj < 8; ++jj) acc[rt][jj] = (f32x4){0.f, 0.f, 0.f, 0.f};
        #pragma unroll
        for (int ks = 0; ks < 2; ++ks)
            #pragma unroll
            for (int rt = 0; rt < 2; ++rt)
                #pragma unroll
                for (int jj = 0; jj < 8; ++jj)
                    acc[rt][jj] = __builtin_amdgcn_mfma_f32_16x16x32_bf16(ka[rt][ks], qf[jj][ks], acc[rt][jj], 0, 0, 0);

        #pragma unroll
        for (int rt = 0; rt < 2; ++rt)
            #pragma unroll
            for (int jj = 0; jj < 8; ++jj) {
                const int j = wq * 1024 + jt * 128 + jj * 16 + l15;
                #pragma unroll
                for (int rg = 0; rg < 4; ++rg) {
                    if (acc[rt][jj][rg] >= th[rt][rg]) {
                        int rowl = rt * 16 + quad * 4 + rg;     // 0..31
                        int sl = atomicAdd(&cnt[rowl], 1);
                        if (sl < SLOTS) bkt[rowl * SSTR + sl] = j;
                    }
                }
            }
    }
    __syncthreads();

    // ------------------ exact fp32 rescore (L2-hot q/k fp32) ---------------
    {
        int r = tid >> 3, sub = tid & 7;
        int n = min(cnt[r], SLOTS);
        const float* krow = ktf + ((size_t)b * TT + ib * 32 + r) * CH;
        for (int m = sub; m < n; m += 8) {
            int j = bkt[r * SSTR + m];
            const float* qrow = qtf + ((size_t)b * TT + j) * CH;
            float wv = 0.f;
            #pragma unroll
            for (int c4 = 0; c4 < 16; ++c4) {
                float4 kv = *(const float4*)&krow[c4 * 4];
                float4 qv = *(const float4*)&qrow[c4 * 4];
                wv = fmaf(kv.x, qv.x, wv); wv = fmaf(kv.y, qv.y, wv);
                wv = fmaf(kv.z, qv.z, wv); wv = fmaf(kv.w, qv.w, wv);
            }
            wbf[r * SSTR + m] = wv;
        }
    }
    __syncthreads();

    if (tid < 32) {
        int n = min(cnt[tid], SLOTS);
        float s9[9]; int si9[9];
        #pragma unroll
        for (int k = 0; k < 9; ++k) { s9[k] = NEG_INF; si9[k] = 0x7fffffff; }
        #pragma unroll 1
        for (int m = 0; m < n; ++m) insert9x(wbf[tid * SSTR + m], bkt[tid * SSTR + m], s9, si9);
        int* orow = idxout + ((size_t)b * TT + ib * 32 + tid) * KNN;
        #pragma unroll
        for (int m = 0; m < 9; ++m) orow[m] = si9[8 - m];
    }
}

// ---------------------------------------------------------------------------
// K3: out[b][o][t] = conv_b[o] + sum_kk u_bf16[b][kk][idx[t][kk]][o]
// ---------------------------------------------------------------------------
__global__ __launch_bounds__(256) void gather_conv_kernel(
        const unsigned short* __restrict__ ub, const int* __restrict__ idxin,
        const float* __restrict__ conv_b, float* __restrict__ out) {
    __shared__ int   sidx[64 * KNN];
    __shared__ float cb[CH];
    const int b   = blockIdx.x & 7;
    const int tb  = blockIdx.x >> 3;
    const int tid = threadIdx.x;

    if (tid < CH) cb[tid] = conv_b[tid];
    const int* ig = idxin + ((size_t)b * TT + tb * 64) * KNN;
    for (int l = tid; l < 64 * KNN; l += 256) sidx[l] = ig[l];
    __syncthreads();

    const int tl = tid & 63;
    const int og = tid >> 6;
    const int o0 = og * 16;

    float acc[16];
    #pragma unroll
    for (int q = 0; q < 16; ++q) acc[q] = cb[o0 + q];

    #pragma unroll
    for (int kk = 0; kk < KNN; ++kk) {
        int j = sidx[tl * KNN + kk];
        const unsigned short* up = ub + (((size_t)(b * KNN + kk)) * TT + j) * CH + o0;
        #pragma unroll
        for (int q8 = 0; q8 < 2; ++q8) {
            uint4 raw = *(const uint4*)&up[q8 * 8];
            unsigned rw[4] = {raw.x, raw.y, raw.z, raw.w};
            #pragma unroll
            for (int p = 0; p < 4; ++p) {
                acc[q8 * 8 + 2 * p]     += __uint_as_float(rw[p] << 16);
                acc[q8 * 8 + 2 * p + 1] += __uint_as_float(rw[p] & 0xFFFF0000u);
            }
        }
    }
    const int t = tb * 64 + tl;
    #pragma unroll
    for (int q = 0; q < 16; ++q)
        out[((size_t)b * CH + o0 + q) * TT + t] = acc[q];
}

// ---------------------------------------------------------------------------
extern "C" void kernel_launch(void* const* d_in, const int* in_sizes, int n_in,
                              void* d_out, int out_size, void* d_ws, size_t ws_size,
                              hipStream_t stream) {
    const float* x   = (const float*)d_in[0];
    const float* Wq  = (const float*)d_in[1];
    const float* Wk  = (const float*)d_in[2];
    const float* Wv  = (const float*)d_in[3];
    const float* cw  = (const float*)d_in[4];
    const float* cbp = (const float*)d_in[5];

    float* ws = (float*)d_ws;
    unsigned short* ub  = (unsigned short*)(ws + OFF_UB);
    float* qtf          = ws + OFF_QTF;
    float* ktf          = ws + OFF_KTF;
    unsigned short* qtb = (unsigned short*)(ws + OFF_QTB);
    unsigned short* ktb = (unsigned short*)(ws + OFF_KTB);
    int*   idx          = (int*)(ws + OFF_IDX);
    float* cwp          = ws + OFF_CWP;
    float* out          = (float*)d_out;

    repack_cw_kernel<<<(KNN * CH * CH + 255) / 256, 256, 0, stream>>>(cw, cwp);
    qkvu_kernel<<<BB * 64, 256, 0, stream>>>(x, Wq, Wk, Wv, cwp, qtf, ktf, qtb, ktb, ub);
    sim_topk_kernel<<<BB * 128, 256, 0, stream>>>(qtb, ktb, qtf, ktf, idx);
    gather_conv_kernel<<<BB * 64, 256, 0, stream>>>(ub, idx, cbp, out);
}

// Round 14
// 288.054 us; speedup vs baseline: 1.2450x; 1.2450x over previous
//
#include <hip/hip_runtime.h>
#include <hip/hip_bf16.h>
#include <cstdint>

// Problem constants
#define BB  8
#define CH  64
#define TT  4096
#define KNN 9
#define NEG_INF (-3.402823466e38f)
#define SLOTS 96          // candidate bucket per row (2 halves, insert2 θ looser)
#define SSTR  97          // padded LDS stride (odd -> conflict-free scans)
#define KTH   12          // θ = 12th largest of per-(row,half) lane-union

typedef short  s16x8 __attribute__((ext_vector_type(8)));   // 8 bf16 MFMA frag
typedef float  f32x4 __attribute__((ext_vector_type(4)));   // MFMA acc

// Workspace layout (float units) — end 16,060,416 floats = 64.2 MB
constexpr size_t OFF_UB  = 0;                                  // u bf16 [B][9][T][C] ushort
constexpr size_t OFF_QTF = (size_t)BB*KNN*TT*CH/2;             //  9,437,184 qhatT f32 [B][T][C]
constexpr size_t OFF_KTF = OFF_QTF + (size_t)BB*TT*CH;         // 11,534,336 khatT f32
constexpr size_t OFF_QTB = OFF_KTF + (size_t)BB*TT*CH;         // 13,631,488 q bf16 FRAGMENT order
constexpr size_t OFF_KTB = OFF_QTB + (size_t)BB*TT*CH/2;       // 14,680,064 khatT bf16 row-major
constexpr size_t OFF_IDX = OFF_KTB + (size_t)BB*TT*CH/2;       // 15,728,640 idx [B][T][9]
constexpr size_t OFF_CWP = OFF_IDX + (size_t)BB*TT*KNN;        // 16,023,552 cwp [9][64][64]

__device__ __forceinline__ unsigned short f2bf(float f) {
    unsigned u = __float_as_uint(f);
    return (unsigned short)((u + 0x7FFFu + ((u >> 16) & 1u)) >> 16);
}

// value-only ascending top-2 (1 med3 + 1 max) — halves the prefilter VALU
// chain vs insert4. s[0]=2nd largest, s[1]=largest.
__device__ __forceinline__ void insert2(float w, float (&s)[2]) {
    s[0] = __builtin_amdgcn_fmed3f(s[0], s[1], w);
    s[1] = fmaxf(s[1], w);
}

// θ = KTH-th largest of the union of the quad's 16 top-2 lists (destroys
// lists). Union ⊆ (row, half) values ⇒ θ ≤ half's KTH-th ≤ half's 9th
// (KTH=12 ≥ 9). Any row-global top-9 element in this half is within the
// half's top-9 ⇒ ≥ θ ⇒ collected in pass B. Same subset-order-statistic
// argument as r0/r4 (both correctness-proven on this data).
__device__ __forceinline__ float popTheta2(float (&s)[2], int lane) {
    float theta = NEG_INF;
    #pragma unroll 1
    for (int p = 0; p < KTH; ++p) {
        float h = s[1];
        float m = h;
        m = fmaxf(m, __shfl_xor(m, 1));
        m = fmaxf(m, __shfl_xor(m, 2));
        m = fmaxf(m, __shfl_xor(m, 4));
        m = fmaxf(m, __shfl_xor(m, 8));
        unsigned long long bal = __ballot(h == m);
        unsigned qb = (unsigned)((bal >> (lane & 48)) & 0xFFFFull);
        int owner = __ffs(qb) - 1;
        if ((lane & 15) == owner) {
            s[1] = s[0]; s[0] = NEG_INF;
        }
        theta = m;
    }
    return theta;
}

// exact sorted-9 insert, value desc w/ index-asc tiebreak (final sort only)
__device__ __forceinline__ void insert9x(float w, int wi, float (&s)[9], int (&si)[9]) {
    bool c[9];
    #pragma unroll
    for (int k = 0; k < 9; ++k) c[k] = (w > s[k]) || (w == s[k] && wi < si[k]);
    #pragma unroll
    for (int k = 0; k < 8; ++k) si[k] = c[k + 1] ? si[k + 1] : (c[k] ? wi : si[k]);
    si[8] = c[8] ? wi : si[8];
    #pragma unroll
    for (int k = 0; k < 8; ++k) s[k] = c[k + 1] ? s[k + 1] : (c[k] ? w : s[k]);
    s[8] = c[8] ? w : s[8];
}

// ---------------------------------------------------------------------------
// K0: repack conv_w[o][cc*9+kk] -> cwp[kk][cc][o]
// ---------------------------------------------------------------------------
__global__ void repack_cw_kernel(const float* __restrict__ cw, float* __restrict__ cwp) {
    int e = blockIdx.x * blockDim.x + threadIdx.x;
    if (e >= KNN * CH * CH) return;
    int o  = e & 63;
    int cc = (e >> 6) & 63;
    int kk = e >> 12;
    cwp[e] = cw[o * (CH * KNN) + cc * KNN + kk];
}

// ---------------------------------------------------------------------------
// K1: QKV + L2 normalize + u-projection (u bf16) + q/k T-layout fp32 & bf16.
//     q bf16 written in MFMA B-FRAGMENT ORDER (r9 win: 1KB contiguous loads).
// ---------------------------------------------------------------------------
__global__ __launch_bounds__(256) void qkvu_kernel(
        const float* __restrict__ x,
        const float* __restrict__ Wq, const float* __restrict__ Wk, const float* __restrict__ Wv,
        const float* __restrict__ cwp,
        float* __restrict__ qtf, float* __restrict__ ktf,
        unsigned short* __restrict__ qtb, unsigned short* __restrict__ ktb,
        unsigned short* __restrict__ ub) {
    __shared__ __align__(16) float xs[CH * 64];
    __shared__ __align__(16) float vs[CH * 64];
    __shared__ __align__(16) float wl[CH * 64];
    __shared__ float pq[4 * 64], pk[4 * 64];

    const int b   = blockIdx.x >> 6;
    const int tb  = blockIdx.x & 63;
    const int tid = threadIdx.x;

    const float* xb = x + ((size_t)b * CH) * TT + tb * 64;
    #pragma unroll
    for (int m = 0; m < 16; ++m) {
        int l = tid + 256 * m;
        xs[l] = xb[(size_t)(l >> 6) * TT + (l & 63)];
    }
    __syncthreads();

    const int t = tid & 63;
    const int g = __builtin_amdgcn_readfirstlane(tid >> 6);
    const int d0 = g * 16;

    float qa[16], ka[16], va[16];
    #pragma unroll
    for (int dd = 0; dd < 16; ++dd) { qa[dd] = 0.f; ka[dd] = 0.f; va[dd] = 0.f; }

    #pragma unroll 4
    for (int c = 0; c < CH; ++c) {
        float xv = xs[c * 64 + t];
        #pragma unroll
        for (int dd = 0; dd < 16; ++dd) {
            qa[dd] = fmaf(Wq[(d0 + dd) * CH + c], xv, qa[dd]);
            ka[dd] = fmaf(Wk[(d0 + dd) * CH + c], xv, ka[dd]);
            va[dd] = fmaf(Wv[(d0 + dd) * CH + c], xv, va[dd]);
        }
    }

    float sq = 0.f, sk = 0.f;
    #pragma unroll
    for (int dd = 0; dd < 16; ++dd) { sq = fmaf(qa[dd], qa[dd], sq); sk = fmaf(ka[dd], ka[dd], sk); }
    pq[g * 64 + t] = sq;
    pk[g * 64 + t] = sk;
    __syncthreads();

    const float nq = sqrtf(pq[t] + pq[64 + t] + pq[128 + t] + pq[192 + t]);
    const float nk = sqrtf(pk[t] + pk[64 + t] + pk[128 + t] + pk[192 + t]);
    const float isq = 1.0f / fmaxf(nq, 1e-12f);
    const float isk = 1.0f / fmaxf(nk, 1e-12f);

    const size_t tg = (size_t)tb * 64 + t;
    float qn[16], kn[16];
    #pragma unroll
    for (int dd = 0; dd < 16; ++dd) {
        qn[dd] = qa[dd] * isq;
        kn[dd] = ka[dd] * isk;
        vs[(d0 + dd) * 64 + t] = va[dd];
    }
    float* qf = qtf + ((size_t)b * TT + tg) * CH + d0;
    float* kf = ktf + ((size_t)b * TT + tg) * CH + d0;
    #pragma unroll
    for (int p = 0; p < 4; ++p) {
        *(float4*)&qf[p * 4] = make_float4(qn[p*4], qn[p*4+1], qn[p*4+2], qn[p*4+3]);
        *(float4*)&kf[p * 4] = make_float4(kn[p*4], kn[p*4+1], kn[p*4+2], kn[p*4+3]);
    }
    // k bf16: row-major (A-fragments are only 4 loads/kernel in sim)
    unsigned* kh = (unsigned*)(ktb + ((size_t)b * TT + tg) * CH + d0);
    #pragma unroll
    for (int p = 0; p < 8; ++p)
        kh[p] = (unsigned)f2bf(kn[2*p]) | ((unsigned)f2bf(kn[2*p+1]) << 16);

    // q bf16: FRAGMENT order (see r9 comment)
    {
        const int j0   = (int)(tg >> 4);
        const int l15q = (int)tg & 15;
        const int ks   = g >> 1;
        const int q0   = (g & 1) * 2;
        #pragma unroll
        for (int h = 0; h < 2; ++h) {
            unsigned w0 = (unsigned)f2bf(qn[h*8+0]) | ((unsigned)f2bf(qn[h*8+1]) << 16);
            unsigned w1 = (unsigned)f2bf(qn[h*8+2]) | ((unsigned)f2bf(qn[h*8+3]) << 16);
            unsigned w2 = (unsigned)f2bf(qn[h*8+4]) | ((unsigned)f2bf(qn[h*8+5]) << 16);
            unsigned w3 = (unsigned)f2bf(qn[h*8+6]) | ((unsigned)f2bf(qn[h*8+7]) << 16);
            unsigned short* dst = qtb +
                ((((size_t)b * 256 + j0) * 2 + ks) * 64 + ((q0 + h) * 16 + l15q)) * 8;
            *(uint4*)dst = make_uint4(w0, w1, w2, w3);
        }
    }
    __syncthreads();

    const int to = tid & 15;
    const int tt = tid >> 4;
    for (int kk = 0; kk < KNN; ++kk) {
        #pragma unroll
        for (int m = 0; m < 16; ++m) {
            int l = tid + 256 * m;
            wl[l] = cwp[kk * (CH * CH) + l];
        }
        __syncthreads();
        float acc[4][4];
        #pragma unroll
        for (int i = 0; i < 4; ++i)
            #pragma unroll
            for (int j = 0; j < 4; ++j) acc[i][j] = 0.f;

        #pragma unroll 8
        for (int cc = 0; cc < CH; ++cc) {
            float4 wv = *(const float4*)&wl[cc * 64 + 4 * to];
            float4 vv = *(const float4*)&vs[cc * 64 + 4 * tt];
            const float wj[4] = {wv.x, wv.y, wv.z, wv.w};
            const float vi[4] = {vv.x, vv.y, vv.z, vv.w};
            #pragma unroll
            for (int i = 0; i < 4; ++i)
                #pragma unroll
                for (int j = 0; j < 4; ++j) acc[i][j] = fmaf(vi[i], wj[j], acc[i][j]);
        }
        #pragma unroll
        for (int i = 0; i < 4; ++i) {
            size_t row = (size_t)(b * KNN + kk) * TT + tb * 64 + 4 * tt + i;
            unsigned w0 = (unsigned)f2bf(acc[i][0]) | ((unsigned)f2bf(acc[i][1]) << 16);
            unsigned w1 = (unsigned)f2bf(acc[i][2]) | ((unsigned)f2bf(acc[i][3]) << 16);
            *(uint2*)&ub[row * CH + 4 * to] = make_uint2(w0, w1);
        }
        __syncthreads();
    }
}

// ---------------------------------------------------------------------------
// K2: BARRIER-FREE bf16-MFMA sim + top-2 prefilter + θ-collect + exact rescore
//     EXACT r9 structure (proven 139.6 µs: grid 512 = b(8) x ib(64), 64-row
//     blocks, 4 waves, wave (w2r,w2c) = row-half x col-half, fragment-order
//     contiguous q loads, launch_bounds(256,2) — the allocator's known-good
//     regime). Round-14 change: insert4 -> insert2 (prefilter VALU chain
//     halves; r4-proven mechanics & correctness with even looser θ).
//     θ per (row, half) from quad's 16-lane top-2 union, KTH=12.
//     SLOTS 48 -> 96 (looser θ -> more pass-B candidates), stride 97.
// ---------------------------------------------------------------------------
__global__ __launch_bounds__(256, 2) void sim_topk_kernel(
        const unsigned short* __restrict__ qtb, const unsigned short* __restrict__ ktb,
        const float* __restrict__ qtf, const float* __restrict__ ktf,
        int* __restrict__ idxout) {
    __shared__ int   cnt[64];
    __shared__ int   bkt[64 * SSTR];
    __shared__ float wbf[64 * SSTR];

    const int b    = blockIdx.x & 7;
    const int ib   = blockIdx.x >> 3;      // 0..63
    const int tid  = threadIdx.x;
    const int lane = tid & 63;
    const int w    = tid >> 6;             // wave 0..3
    const int w2r  = w >> 1;               // row half
    const int w2c  = w & 1;                // col half
    const int quad = lane >> 4;
    const int l15  = lane & 15;

    if (tid < 64) cnt[tid] = 0;
    __syncthreads();

    // k A-fragments in registers: rows w2r*32 + rt*16 + l15, k = quad*8+ks*32
    const unsigned short* kb = ktb + ((size_t)b * TT + ib * 64 + w2r * 32) * CH;
    s16x8 ka[2][2];
    #pragma unroll
    for (int rt = 0; rt < 2; ++rt)
        #pragma unroll
        for (int ks = 0; ks < 2; ++ks)
            ka[rt][ks] = *(const s16x8*)(kb + (size_t)(rt * 16 + l15) * CH + ks * 32 + quad * 8);

    // fragment-order q base for this batch & col-half:
    // frag[(b*256 + j0)*2 + ks][lane]*8, j0 = w2c*128 + jt*8 + jj
    const unsigned short* qfb = qtb + (((size_t)b * 256 + (size_t)w2c * 128) * 2) * 512
                                + (size_t)lane * 8;

    float s[2][4][2];
    #pragma unroll
    for (int rt = 0; rt < 2; ++rt)
        #pragma unroll
        for (int rg = 0; rg < 4; ++rg) { s[rt][rg][0] = NEG_INF; s[rt][rg][1] = NEG_INF; }

    // ------------------ PASS A: values-only top-2 (no barriers) ------------
    for (int jt = 0; jt < 16; ++jt) {
        const unsigned short* qrow = qfb + (size_t)(jt * 8) * 1024;  // j0 step=2*512
        s16x8 qf[8][2];
        #pragma unroll
        for (int jj = 0; jj < 8; ++jj)
            #pragma unroll
            for (int ks = 0; ks < 2; ++ks)
                qf[jj][ks] = *(const s16x8*)(qrow + (size_t)(jj * 2 + ks) * 512);

        f32x4 acc[2][8];
        #pragma unroll
        for (int rt = 0; rt < 2; ++rt)
            #pragma unroll
            for (int jj = 0; jj < 8; ++jj) acc[rt][jj] = (f32x4){0.f, 0.f, 0.f, 0.f};
        #pragma unroll
        for (int ks = 0; ks < 2; ++ks)
            #pragma unroll
            for (int rt = 0; rt < 2; ++rt)
                #pragma unroll
                for (int jj = 0; jj < 8; ++jj)
                    acc[rt][jj] = __builtin_amdgcn_mfma_f32_16x16x32_bf16(ka[rt][ks], qf[jj][ks], acc[rt][jj], 0, 0, 0);

        #pragma unroll
        for (int rt = 0; rt < 2; ++rt)
            #pragma unroll
            for (int jj = 0; jj < 8; ++jj) {
                insert2(acc[rt][jj][0], s[rt][0]);
                insert2(acc[rt][jj][1], s[rt][1]);
                insert2(acc[rt][jj][2], s[rt][2]);
                insert2(acc[rt][jj][3], s[rt][3]);
            }
    }

    // per-(row,half) θ — valid per half; no cross-wave merge needed
    float th[2][4];
    #pragma unroll
    for (int rt = 0; rt < 2; ++rt) {
        th[rt][0] = popTheta2(s[rt][0], lane);
        th[rt][1] = popTheta2(s[rt][1], lane);
        th[rt][2] = popTheta2(s[rt][2], lane);
        th[rt][3] = popTheta2(s[rt][3], lane);
    }

    // ------------------ PASS B: recompute (bitwise-identical) + collect ----
    for (int jt = 0; jt < 16; ++jt) {
        const unsigned short* qrow = qfb + (size_t)(jt * 8) * 1024;
        s16x8 qf[8][2];
        #pragma unroll
        for (int jj = 0; jj < 8; ++jj)
            #pragma unroll
            for (int ks = 0; ks < 2; ++ks)
                qf[jj][ks] = *(const s16x8*)(qrow + (size_t)(jj * 2 + ks) * 512);

        f32x4 acc[2][8];
        #pragma unroll
        for (int rt = 0; rt < 2; ++rt)
            #pragma unroll
            for (int jj = 0; jj < 8; ++jj) acc[rt][jj] = (f32x4){0.f, 0.f, 0.f, 0.f};
        #pragma unroll
        for (int ks = 0; ks < 2; ++ks)
            #pragma unroll
            for (int rt = 0; rt < 2; ++rt)
                #pragma unroll
                for (int jj = 0; jj < 8; ++jj)
                    acc[rt][jj] = __builtin_amdgcn_mfma_f32_16x16x32_bf16(ka[rt][ks], qf[jj][ks], acc[rt][jj], 0, 0, 0);

        #pragma unroll
        for (int rt = 0; rt < 2; ++rt)
            #pragma unroll
            for (int jj = 0; jj < 8; ++jj) {
                const int j = w2c * 2048 + jt * 128 + jj * 16 + l15;
                #pragma unroll
                for (int rg = 0; rg < 4; ++rg) {
                    if (acc[rt][jj][rg] >= th[rt][rg]) {
                        int rowl = w2r * 32 + rt * 16 + quad * 4 + rg;
                        int sl = atomicAdd(&cnt[rowl], 1);
                        if (sl < SLOTS) bkt[rowl * SSTR + sl] = j;
                    }
                }
            }
    }
    __syncthreads();

    // ------------------ exact fp32 rescore (L2-hot q/k fp32) ---------------
    {
        int r = tid >> 2, sub = tid & 3;
        int n = min(cnt[r], SLOTS);
        const float* krow = ktf + ((size_t)b * TT + ib * 64 + r) * CH;
        for (int m = sub; m < n; m += 4) {
            int j = bkt[r * SSTR + m];
            const float* qrow = qtf + ((size_t)b * TT + j) * CH;
            float wv = 0.f;
            #pragma unroll
            for (int c4 = 0; c4 < 16; ++c4) {
                float4 kv = *(const float4*)&krow[c4 * 4];
                float4 qv = *(const float4*)&qrow[c4 * 4];
                wv = fmaf(kv.x, qv.x, wv); wv = fmaf(kv.y, qv.y, wv);
                wv = fmaf(kv.z, qv.z, wv); wv = fmaf(kv.w, qv.w, wv);
            }
            wbf[r * SSTR + m] = wv;
        }
    }
    __syncthreads();

    if (tid < 64) {
        int n = min(cnt[tid], SLOTS);
        float s9[9]; int si9[9];
        #pragma unroll
        for (int k = 0; k < 9; ++k) { s9[k] = NEG_INF; si9[k] = 0x7fffffff; }
        #pragma unroll 1
        for (int m = 0; m < n; ++m) insert9x(wbf[tid * SSTR + m], bkt[tid * SSTR + m], s9, si9);
        int* orow = idxout + ((size_t)b * TT + ib * 64 + tid) * KNN;
        #pragma unroll
        for (int m = 0; m < 9; ++m) orow[m] = si9[8 - m];
    }
}

// ---------------------------------------------------------------------------
// K3: out[b][o][t] = conv_b[o] + sum_kk u_bf16[b][kk][idx[t][kk]][o]
// ---------------------------------------------------------------------------
__global__ __launch_bounds__(256) void gather_conv_kernel(
        const unsigned short* __restrict__ ub, const int* __restrict__ idxin,
        const float* __restrict__ conv_b, float* __restrict__ out) {
    __shared__ int   sidx[64 * KNN];
    __shared__ float cb[CH];
    const int b   = blockIdx.x & 7;
    const int tb  = blockIdx.x >> 3;
    const int tid = threadIdx.x;

    if (tid < CH) cb[tid] = conv_b[tid];
    const int* ig = idxin + ((size_t)b * TT + tb * 64) * KNN;
    for (int l = tid; l < 64 * KNN; l += 256) sidx[l] = ig[l];
    __syncthreads();

    const int tl = tid & 63;
    const int og = tid >> 6;
    const int o0 = og * 16;

    float acc[16];
    #pragma unroll
    for (int q = 0; q < 16; ++q) acc[q] = cb[o0 + q];

    #pragma unroll
    for (int kk = 0; kk < KNN; ++kk) {
        int j = sidx[tl * KNN + kk];
        const unsigned short* up = ub + (((size_t)(b * KNN + kk)) * TT + j) * CH + o0;
        #pragma unroll
        for (int q8 = 0; q8 < 2; ++q8) {
            uint4 raw = *(const uint4*)&up[q8 * 8];
            unsigned rw[4] = {raw.x, raw.y, raw.z, raw.w};
            #pragma unroll
            for (int p = 0; p < 4; ++p) {
                acc[q8 * 8 + 2 * p]     += __uint_as_float(rw[p] << 16);
                acc[q8 * 8 + 2 * p + 1] += __uint_as_float(rw[p] & 0xFFFF0000u);
            }
        }
    }
    const int t = tb * 64 + tl;
    #pragma unroll
    for (int q = 0; q < 16; ++q)
        out[((size_t)b * CH + o0 + q) * TT + t] = acc[q];
}

// ---------------------------------------------------------------------------
extern "C" void kernel_launch(void* const* d_in, const int* in_sizes, int n_in,
                              void* d_out, int out_size, void* d_ws, size_t ws_size,
                              hipStream_t stream) {
    const float* x   = (const float*)d_in[0];
    const float* Wq  = (const float*)d_in[1];
    const float* Wk  = (const float*)d_in[2];
    const float* Wv  = (const float*)d_in[3];
    const float* cw  = (const float*)d_in[4];
    const float* cbp = (const float*)d_in[5];

    float* ws = (float*)d_ws;
    unsigned short* ub  = (unsigned short*)(ws + OFF_UB);
    float* qtf          = ws + OFF_QTF;
    float* ktf          = ws + OFF_KTF;
    unsigned short* qtb = (unsigned short*)(ws + OFF_QTB);
    unsigned short* ktb = (unsigned short*)(ws + OFF_KTB);
    int*   idx          = (int*)(ws + OFF_IDX);
    float* cwp          = ws + OFF_CWP;
    float* out          = (float*)d_out;

    repack_cw_kernel<<<(KNN * CH * CH + 255) / 256, 256, 0, stream>>>(cw, cwp);
    qkvu_kernel<<<BB * 64, 256, 0, stream>>>(x, Wq, Wk, Wv, cwp, qtf, ktf, qtb, ktb, ub);
    sim_topk_kernel<<<BB * 64, 256, 0, stream>>>(qtb, ktb, qtf, ktf, idx);
    gather_conv_kernel<<<BB * 64, 256, 0, stream>>>(ub, idx, cbp, out);
}

// Round 15
// 263.176 us; speedup vs baseline: 1.3627x; 1.0945x over previous
//
#include <hip/hip_runtime.h>
#include <hip/hip_bf16.h>
#include <cstdint>

// Problem constants
#define BB  8
#define CH  64
#define TT  4096
#define KNN 9
#define NEG_INF (-3.402823466e38f)
#define SLOTS 96          // candidate bucket per row (2 halves, insert2 θ looser)
#define SSTR  97          // padded LDS stride (odd -> conflict-free scans)
#define KTH   12          // θ = 12th largest of per-(row,half) lane-union

typedef short  s16x8 __attribute__((ext_vector_type(8)));   // 8 bf16 MFMA frag
typedef float  f32x4 __attribute__((ext_vector_type(4)));   // MFMA acc

// Workspace layout (float units) — end 16,060,416 floats = 64.2 MB
constexpr size_t OFF_UB  = 0;                                  // u bf16 [B][9][T][C] ushort
constexpr size_t OFF_QTF = (size_t)BB*KNN*TT*CH/2;             //  9,437,184 qhatT f32 [B][T][C]
constexpr size_t OFF_KTF = OFF_QTF + (size_t)BB*TT*CH;         // 11,534,336 khatT f32
constexpr size_t OFF_QTB = OFF_KTF + (size_t)BB*TT*CH;         // 13,631,488 q bf16 FRAGMENT order
constexpr size_t OFF_KTB = OFF_QTB + (size_t)BB*TT*CH/2;       // 14,680,064 khatT bf16 row-major
constexpr size_t OFF_IDX = OFF_KTB + (size_t)BB*TT*CH/2;       // 15,728,640 idx [B][T][9]
constexpr size_t OFF_CWP = OFF_IDX + (size_t)BB*TT*KNN;        // 16,023,552 cwb bf16 frags (74KB)

__device__ __forceinline__ unsigned short f2bf(float f) {
    unsigned u = __float_as_uint(f);
    return (unsigned short)((u + 0x7FFFu + ((u >> 16) & 1u)) >> 16);
}

// value-only ascending top-2 (1 med3 + 1 max). s[0]=2nd largest, s[1]=largest.
__device__ __forceinline__ void insert2(float w, float (&s)[2]) {
    s[0] = __builtin_amdgcn_fmed3f(s[0], s[1], w);
    s[1] = fmaxf(s[1], w);
}

// θ = KTH-th largest of the union of the quad's 16 top-2 lists (destroys
// lists). Union ⊆ (row, half) values ⇒ θ ≤ half's KTH-th ≤ half's 9th
// (KTH=12 ≥ 9). Any row-global top-9 element in this half is within the
// half's top-9 ⇒ ≥ θ ⇒ collected in pass B. r14-proven.
__device__ __forceinline__ float popTheta2(float (&s)[2], int lane) {
    float theta = NEG_INF;
    #pragma unroll 1
    for (int p = 0; p < KTH; ++p) {
        float h = s[1];
        float m = h;
        m = fmaxf(m, __shfl_xor(m, 1));
        m = fmaxf(m, __shfl_xor(m, 2));
        m = fmaxf(m, __shfl_xor(m, 4));
        m = fmaxf(m, __shfl_xor(m, 8));
        unsigned long long bal = __ballot(h == m);
        unsigned qb = (unsigned)((bal >> (lane & 48)) & 0xFFFFull);
        int owner = __ffs(qb) - 1;
        if ((lane & 15) == owner) {
            s[1] = s[0]; s[0] = NEG_INF;
        }
        theta = m;
    }
    return theta;
}

// exact sorted-9 insert, value desc w/ index-asc tiebreak (final sort only)
__device__ __forceinline__ void insert9x(float w, int wi, float (&s)[9], int (&si)[9]) {
    bool c[9];
    #pragma unroll
    for (int k = 0; k < 9; ++k) c[k] = (w > s[k]) || (w == s[k] && wi < si[k]);
    #pragma unroll
    for (int k = 0; k < 8; ++k) si[k] = c[k + 1] ? si[k + 1] : (c[k] ? wi : si[k]);
    si[8] = c[8] ? wi : si[8];
    #pragma unroll
    for (int k = 0; k < 8; ++k) s[k] = c[k + 1] ? s[k + 1] : (c[k] ? w : s[k]);
    s[8] = c[8] ? w : s[8];
}

// ---------------------------------------------------------------------------
// K0: repack conv_w into bf16 MFMA B-FRAGMENT order:
//     cwb[((kk*4 + ot)*2 + ks)*64 + lane][i] = bf16(cw[o][cc*9 + kk])
//     with o = ot*16 + (lane&15), cc = ks*32 + (lane>>4)*8 + i.
// ---------------------------------------------------------------------------
__global__ void repack_cw_kernel(const float* __restrict__ cw, unsigned short* __restrict__ cwb) {
    int e = blockIdx.x * blockDim.x + threadIdx.x;      // (kk,ot,ks,lane)
    if (e >= KNN * 4 * 2 * 64) return;
    int lane = e & 63;
    int ks   = (e >> 6) & 1;
    int ot   = (e >> 7) & 3;
    int kk   = e >> 9;
    int o    = ot * 16 + (lane & 15);
    int cc0  = ks * 32 + (lane >> 4) * 8;
    unsigned short* dst = cwb + (size_t)e * 8;
    #pragma unroll
    for (int i = 0; i < 8; ++i)
        dst[i] = f2bf(cw[o * (CH * KNN) + (cc0 + i) * KNN + kk]);
}

// ---------------------------------------------------------------------------
// K1: QKV (fp32 VALU, precision-critical) + L2 normalize + q/k stores +
//     *** u-projection on MFMA *** (round-15): v stored as bf16 [t][cc] in
//     LDS; wave g = m-tile (16 t-rows); per kk: 8 MFMA (4 o-tiles x 2 k-chunks)
//     replaces 9216 scalar fmaf/thread; kk loop is BARRIER-FREE (was 18
//     barriers + 16KB wl staging per block). q bf16 still written in MFMA
//     B-fragment order (r9 win).
// ---------------------------------------------------------------------------
__global__ __launch_bounds__(256) void qkvu_kernel(
        const float* __restrict__ x,
        const float* __restrict__ Wq, const float* __restrict__ Wk, const float* __restrict__ Wv,
        const unsigned short* __restrict__ cwb,
        float* __restrict__ qtf, float* __restrict__ ktf,
        unsigned short* __restrict__ qtb, unsigned short* __restrict__ ktb,
        unsigned short* __restrict__ ub) {
    __shared__ __align__(16) float xs[CH * 64];
    __shared__ __align__(16) unsigned short vsb[64 * 64];   // v bf16, [t][cc]
    __shared__ float pq[4 * 64], pk[4 * 64];

    const int b   = blockIdx.x >> 6;
    const int tb  = blockIdx.x & 63;
    const int tid = threadIdx.x;

    const float* xb = x + ((size_t)b * CH) * TT + tb * 64;
    #pragma unroll
    for (int m = 0; m < 16; ++m) {
        int l = tid + 256 * m;
        xs[l] = xb[(size_t)(l >> 6) * TT + (l & 63)];
    }
    __syncthreads();

    const int t = tid & 63;
    const int g = __builtin_amdgcn_readfirstlane(tid >> 6);
    const int d0 = g * 16;

    float qa[16], ka[16], va[16];
    #pragma unroll
    for (int dd = 0; dd < 16; ++dd) { qa[dd] = 0.f; ka[dd] = 0.f; va[dd] = 0.f; }

    #pragma unroll 4
    for (int c = 0; c < CH; ++c) {
        float xv = xs[c * 64 + t];
        #pragma unroll
        for (int dd = 0; dd < 16; ++dd) {
            qa[dd] = fmaf(Wq[(d0 + dd) * CH + c], xv, qa[dd]);
            ka[dd] = fmaf(Wk[(d0 + dd) * CH + c], xv, ka[dd]);
            va[dd] = fmaf(Wv[(d0 + dd) * CH + c], xv, va[dd]);
        }
    }

    float sq = 0.f, sk = 0.f;
    #pragma unroll
    for (int dd = 0; dd < 16; ++dd) { sq = fmaf(qa[dd], qa[dd], sq); sk = fmaf(ka[dd], ka[dd], sk); }
    pq[g * 64 + t] = sq;
    pk[g * 64 + t] = sk;
    __syncthreads();

    const float nq = sqrtf(pq[t] + pq[64 + t] + pq[128 + t] + pq[192 + t]);
    const float nk = sqrtf(pk[t] + pk[64 + t] + pk[128 + t] + pk[192 + t]);
    const float isq = 1.0f / fmaxf(nq, 1e-12f);
    const float isk = 1.0f / fmaxf(nk, 1e-12f);

    const size_t tg = (size_t)tb * 64 + t;
    float qn[16], kn[16];
    #pragma unroll
    for (int dd = 0; dd < 16; ++dd) {
        qn[dd] = qa[dd] * isq;
        kn[dd] = ka[dd] * isk;
    }
    // v bf16 transposed [t][cc]: thread owns cc = d0..d0+15 of row t (32B contig)
    {
        unsigned* vh = (unsigned*)&vsb[t * 64 + d0];
        #pragma unroll
        for (int p = 0; p < 8; ++p)
            vh[p] = (unsigned)f2bf(va[2*p]) | ((unsigned)f2bf(va[2*p+1]) << 16);
    }
    float* qf = qtf + ((size_t)b * TT + tg) * CH + d0;
    float* kf = ktf + ((size_t)b * TT + tg) * CH + d0;
    #pragma unroll
    for (int p = 0; p < 4; ++p) {
        *(float4*)&qf[p * 4] = make_float4(qn[p*4], qn[p*4+1], qn[p*4+2], qn[p*4+3]);
        *(float4*)&kf[p * 4] = make_float4(kn[p*4], kn[p*4+1], kn[p*4+2], kn[p*4+3]);
    }
    // k bf16: row-major (A-fragments are only 4 loads/kernel in sim)
    unsigned* kh = (unsigned*)(ktb + ((size_t)b * TT + tg) * CH + d0);
    #pragma unroll
    for (int p = 0; p < 8; ++p)
        kh[p] = (unsigned)f2bf(kn[2*p]) | ((unsigned)f2bf(kn[2*p+1]) << 16);

    // q bf16: FRAGMENT order (see r9 comment)
    {
        const int j0   = (int)(tg >> 4);
        const int l15q = (int)tg & 15;
        const int ks   = g >> 1;
        const int q0   = (g & 1) * 2;
        #pragma unroll
        for (int h = 0; h < 2; ++h) {
            unsigned w0 = (unsigned)f2bf(qn[h*8+0]) | ((unsigned)f2bf(qn[h*8+1]) << 16);
            unsigned w1 = (unsigned)f2bf(qn[h*8+2]) | ((unsigned)f2bf(qn[h*8+3]) << 16);
            unsigned w2 = (unsigned)f2bf(qn[h*8+4]) | ((unsigned)f2bf(qn[h*8+5]) << 16);
            unsigned w3 = (unsigned)f2bf(qn[h*8+6]) | ((unsigned)f2bf(qn[h*8+7]) << 16);
            unsigned short* dst = qtb +
                ((((size_t)b * 256 + j0) * 2 + ks) * 64 + ((q0 + h) * 16 + l15q)) * 8;
            *(uint4*)dst = make_uint4(w0, w1, w2, w3);
        }
    }
    __syncthreads();

    // ---- u-projection via MFMA: u[t][o] = sum_cc v[t][cc] * cw[o][cc] ----
    // Wave g owns t-rows [g*16, +16). A-frag: lane(quad,l15) holds row l15,
    // k = quad*8 + ks*32. D: row = quad*4 + reg, col = l15.
    const int l15 = t & 15;
    const int quad = t >> 4;
    s16x8 av[2];
    #pragma unroll
    for (int ks = 0; ks < 2; ++ks)
        av[ks] = *(const s16x8*)&vsb[(g * 16 + l15) * 64 + ks * 32 + quad * 8];

    #pragma unroll 1
    for (int kk = 0; kk < KNN; ++kk) {
        f32x4 ua[4];
        #pragma unroll
        for (int ot = 0; ot < 4; ++ot) ua[ot] = (f32x4){0.f, 0.f, 0.f, 0.f};
        #pragma unroll
        for (int ks = 0; ks < 2; ++ks)
            #pragma unroll
            for (int ot = 0; ot < 4; ++ot) {
                s16x8 bw = *(const s16x8*)(cwb + ((((size_t)kk * 4 + ot) * 2 + ks) * 64 + t) * 8);
                ua[ot] = __builtin_amdgcn_mfma_f32_16x16x32_bf16(av[ks], bw, ua[ot], 0, 0, 0);
            }
        const size_t rowb = (size_t)(b * KNN + kk) * TT + tb * 64 + g * 16 + quad * 4;
        #pragma unroll
        for (int ot = 0; ot < 4; ++ot)
            #pragma unroll
            for (int r = 0; r < 4; ++r)
                ub[(rowb + r) * CH + ot * 16 + l15] = f2bf(ua[ot][r]);
    }
}

// ---------------------------------------------------------------------------
// K2: BARRIER-FREE bf16-MFMA sim + top-2 prefilter + θ-collect + exact rescore
//     EXACT r14 kernel (proven 135 µs) — untouched this round.
// ---------------------------------------------------------------------------
__global__ __launch_bounds__(256, 2) void sim_topk_kernel(
        const unsigned short* __restrict__ qtb, const unsigned short* __restrict__ ktb,
        const float* __restrict__ qtf, const float* __restrict__ ktf,
        int* __restrict__ idxout) {
    __shared__ int   cnt[64];
    __shared__ int   bkt[64 * SSTR];
    __shared__ float wbf[64 * SSTR];

    const int b    = blockIdx.x & 7;
    const int ib   = blockIdx.x >> 3;      // 0..63
    const int tid  = threadIdx.x;
    const int lane = tid & 63;
    const int w    = tid >> 6;             // wave 0..3
    const int w2r  = w >> 1;               // row half
    const int w2c  = w & 1;                // col half
    const int quad = lane >> 4;
    const int l15  = lane & 15;

    if (tid < 64) cnt[tid] = 0;
    __syncthreads();

    // k A-fragments in registers: rows w2r*32 + rt*16 + l15, k = quad*8+ks*32
    const unsigned short* kb = ktb + ((size_t)b * TT + ib * 64 + w2r * 32) * CH;
    s16x8 ka[2][2];
    #pragma unroll
    for (int rt = 0; rt < 2; ++rt)
        #pragma unroll
        for (int ks = 0; ks < 2; ++ks)
            ka[rt][ks] = *(const s16x8*)(kb + (size_t)(rt * 16 + l15) * CH + ks * 32 + quad * 8);

    // fragment-order q base for this batch & col-half:
    // frag[(b*256 + j0)*2 + ks][lane]*8, j0 = w2c*128 + jt*8 + jj
    const unsigned short* qfb = qtb + (((size_t)b * 256 + (size_t)w2c * 128) * 2) * 512
                                + (size_t)lane * 8;

    float s[2][4][2];
    #pragma unroll
    for (int rt = 0; rt < 2; ++rt)
        #pragma unroll
        for (int rg = 0; rg < 4; ++rg) { s[rt][rg][0] = NEG_INF; s[rt][rg][1] = NEG_INF; }

    // ------------------ PASS A: values-only top-2 (no barriers) ------------
    for (int jt = 0; jt < 16; ++jt) {
        const unsigned short* qrow = qfb + (size_t)(jt * 8) * 1024;  // j0 step=2*512
        s16x8 qf[8][2];
        #pragma unroll
        for (int jj = 0; jj < 8; ++jj)
            #pragma unroll
            for (int ks = 0; ks < 2; ++ks)
                qf[jj][ks] = *(const s16x8*)(qrow + (size_t)(jj * 2 + ks) * 512);

        f32x4 acc[2][8];
        #pragma unroll
        for (int rt = 0; rt < 2; ++rt)
            #pragma unroll
            for (int jj = 0; jj < 8; ++jj) acc[rt][jj] = (f32x4){0.f, 0.f, 0.f, 0.f};
        #pragma unroll
        for (int ks = 0; ks < 2; ++ks)
            #pragma unroll
            for (int rt = 0; rt < 2; ++rt)
                #pragma unroll
                for (int jj = 0; jj < 8; ++jj)
                    acc[rt][jj] = __builtin_amdgcn_mfma_f32_16x16x32_bf16(ka[rt][ks], qf[jj][ks], acc[rt][jj], 0, 0, 0);

        #pragma unroll
        for (int rt = 0; rt < 2; ++rt)
            #pragma unroll
            for (int jj = 0; jj < 8; ++jj) {
                insert2(acc[rt][jj][0], s[rt][0]);
                insert2(acc[rt][jj][1], s[rt][1]);
                insert2(acc[rt][jj][2], s[rt][2]);
                insert2(acc[rt][jj][3], s[rt][3]);
            }
    }

    // per-(row,half) θ — valid per half; no cross-wave merge needed
    float th[2][4];
    #pragma unroll
    for (int rt = 0; rt < 2; ++rt) {
        th[rt][0] = popTheta2(s[rt][0], lane);
        th[rt][1] = popTheta2(s[rt][1], lane);
        th[rt][2] = popTheta2(s[rt][2], lane);
        th[rt][3] = popTheta2(s[rt][3], lane);
    }

    // ------------------ PASS B: recompute (bitwise-identical) + collect ----
    for (int jt = 0; jt < 16; ++jt) {
        const unsigned short* qrow = qfb + (size_t)(jt * 8) * 1024;
        s16x8 qf[8][2];
        #pragma unroll
        for (int jj = 0; jj < 8; ++jj)
            #pragma unroll
            for (int ks = 0; ks < 2; ++ks)
                qf[jj][ks] = *(const s16x8*)(qrow + (size_t)(jj * 2 + ks) * 512);

        f32x4 acc[2][8];
        #pragma unroll
        for (int rt = 0; rt < 2; ++rt)
            #pragma unroll
            for (int jj = 0; jj < 8; ++jj) acc[rt][jj] = (f32x4){0.f, 0.f, 0.f, 0.f};
        #pragma unroll
        for (int ks = 0; ks < 2; ++ks)
            #pragma unroll
            for (int rt = 0; rt < 2; ++rt)
                #pragma unroll
                for (int jj = 0; jj < 8; ++jj)
                    acc[rt][jj] = __builtin_amdgcn_mfma_f32_16x16x32_bf16(ka[rt][ks], qf[jj][ks], acc[rt][jj], 0, 0, 0);

        #pragma unroll
        for (int rt = 0; rt < 2; ++rt)
            #pragma unroll
            for (int jj = 0; jj < 8; ++jj) {
                const int j = w2c * 2048 + jt * 128 + jj * 16 + l15;
                #pragma unroll
                for (int rg = 0; rg < 4; ++rg) {
                    if (acc[rt][jj][rg] >= th[rt][rg]) {
                        int rowl = w2r * 32 + rt * 16 + quad * 4 + rg;
                        int sl = atomicAdd(&cnt[rowl], 1);
                        if (sl < SLOTS) bkt[rowl * SSTR + sl] = j;
                    }
                }
            }
    }
    __syncthreads();

    // ------------------ exact fp32 rescore (L2-hot q/k fp32) ---------------
    {
        int r = tid >> 2, sub = tid & 3;
        int n = min(cnt[r], SLOTS);
        const float* krow = ktf + ((size_t)b * TT + ib * 64 + r) * CH;
        for (int m = sub; m < n; m += 4) {
            int j = bkt[r * SSTR + m];
            const float* qrow = qtf + ((size_t)b * TT + j) * CH;
            float wv = 0.f;
            #pragma unroll
            for (int c4 = 0; c4 < 16; ++c4) {
                float4 kv = *(const float4*)&krow[c4 * 4];
                float4 qv = *(const float4*)&qrow[c4 * 4];
                wv = fmaf(kv.x, qv.x, wv); wv = fmaf(kv.y, qv.y, wv);
                wv = fmaf(kv.z, qv.z, wv); wv = fmaf(kv.w, qv.w, wv);
            }
            wbf[r * SSTR + m] = wv;
        }
    }
    __syncthreads();

    if (tid < 64) {
        int n = min(cnt[tid], SLOTS);
        float s9[9]; int si9[9];
        #pragma unroll
        for (int k = 0; k < 9; ++k) { s9[k] = NEG_INF; si9[k] = 0x7fffffff; }
        #pragma unroll 1
        for (int m = 0; m < n; ++m) insert9x(wbf[tid * SSTR + m], bkt[tid * SSTR + m], s9, si9);
        int* orow = idxout + ((size_t)b * TT + ib * 64 + tid) * KNN;
        #pragma unroll
        for (int m = 0; m < 9; ++m) orow[m] = si9[8 - m];
    }
}

// ---------------------------------------------------------------------------
// K3: out[b][o][t] = conv_b[o] + sum_kk u_bf16[b][kk][idx[t][kk]][o]
// ---------------------------------------------------------------------------
__global__ __launch_bounds__(256) void gather_conv_kernel(
        const unsigned short* __restrict__ ub, const int* __restrict__ idxin,
        const float* __restrict__ conv_b, float* __restrict__ out) {
    __shared__ int   sidx[64 * KNN];
    __shared__ float cb[CH];
    const int b   = blockIdx.x & 7;
    const int tb  = blockIdx.x >> 3;
    const int tid = threadIdx.x;

    if (tid < CH) cb[tid] = conv_b[tid];
    const int* ig = idxin + ((size_t)b * TT + tb * 64) * KNN;
    for (int l = tid; l < 64 * KNN; l += 256) sidx[l] = ig[l];
    __syncthreads();

    const int tl = tid & 63;
    const int og = tid >> 6;
    const int o0 = og * 16;

    float acc[16];
    #pragma unroll
    for (int q = 0; q < 16; ++q) acc[q] = cb[o0 + q];

    #pragma unroll
    for (int kk = 0; kk < KNN; ++kk) {
        int j = sidx[tl * KNN + kk];
        const unsigned short* up = ub + (((size_t)(b * KNN + kk)) * TT + j) * CH + o0;
        #pragma unroll
        for (int q8 = 0; q8 < 2; ++q8) {
            uint4 raw = *(const uint4*)&up[q8 * 8];
            unsigned rw[4] = {raw.x, raw.y, raw.z, raw.w};
            #pragma unroll
            for (int p = 0; p < 4; ++p) {
                acc[q8 * 8 + 2 * p]     += __uint_as_float(rw[p] << 16);
                acc[q8 * 8 + 2 * p + 1] += __uint_as_float(rw[p] & 0xFFFF0000u);
            }
        }
    }
    const int t = tb * 64 + tl;
    #pragma unroll
    for (int q = 0; q < 16; ++q)
        out[((size_t)b * CH + o0 + q) * TT + t] = acc[q];
}

// ---------------------------------------------------------------------------
extern "C" void kernel_launch(void* const* d_in, const int* in_sizes, int n_in,
                              void* d_out, int out_size, void* d_ws, size_t ws_size,
                              hipStream_t stream) {
    const float* x   = (const float*)d_in[0];
    const float* Wq  = (const float*)d_in[1];
    const float* Wk  = (const float*)d_in[2];
    const float* Wv  = (const float*)d_in[3];
    const float* cw  = (const float*)d_in[4];
    const float* cbp = (const float*)d_in[5];

    float* ws = (float*)d_ws;
    unsigned short* ub  = (unsigned short*)(ws + OFF_UB);
    float* qtf          = ws + OFF_QTF;
    float* ktf          = ws + OFF_KTF;
    unsigned short* qtb = (unsigned short*)(ws + OFF_QTB);
    unsigned short* ktb = (unsigned short*)(ws + OFF_KTB);
    int*   idx          = (int*)(ws + OFF_IDX);
    unsigned short* cwb = (unsigned short*)(ws + OFF_CWP);
    float* out          = (float*)d_out;

    repack_cw_kernel<<<(KNN * 4 * 2 * 64 + 255) / 256, 256, 0, stream>>>(cw, cwb);
    qkvu_kernel<<<BB * 64, 256, 0, stream>>>(x, Wq, Wk, Wv, cwb, qtf, ktf, qtb, ktb, ub);
    sim_topk_kernel<<<BB * 64, 256, 0, stream>>>(qtb, ktb, qtf, ktf, idx);
    gather_conv_kernel<<<BB * 64, 256, 0, stream>>>(ub, idx, cbp, out);
}

// Round 16
// 256.849 us; speedup vs baseline: 1.3962x; 1.0246x over previous
//
#include <hip/hip_runtime.h>
#include <hip/hip_bf16.h>
#include <cstdint>

// Problem constants
#define BB  8
#define CH  64
#define TT  4096
#define KNN 9
#define NEG_INF (-3.402823466e38f)
#define SLOTS 96          // candidate bucket per row (2 halves, insert2 θ looser)
#define SSTR  97          // padded LDS stride (odd -> conflict-free scans)
#define KTH   12          // θ = 12th largest of per-(row,half) lane-union

typedef short  s16x8 __attribute__((ext_vector_type(8)));   // 8 bf16 MFMA frag
typedef float  f32x4 __attribute__((ext_vector_type(4)));   // MFMA acc

// Workspace layout (float units) — end 16,060,416 floats = 64.2 MB
constexpr size_t OFF_UB  = 0;                                  // u bf16 [B][9][T][C] ushort
constexpr size_t OFF_QTF = (size_t)BB*KNN*TT*CH/2;             //  9,437,184 qhatT f32 [B][T][C]
constexpr size_t OFF_KTF = OFF_QTF + (size_t)BB*TT*CH;         // 11,534,336 khatT f32
constexpr size_t OFF_QTB = OFF_KTF + (size_t)BB*TT*CH;         // 13,631,488 q bf16 FRAGMENT order
constexpr size_t OFF_KTB = OFF_QTB + (size_t)BB*TT*CH/2;       // 14,680,064 khatT bf16 row-major
constexpr size_t OFF_IDX = OFF_KTB + (size_t)BB*TT*CH/2;       // 15,728,640 (unused since r16)
constexpr size_t OFF_CWP = OFF_IDX + (size_t)BB*TT*KNN;        // 16,023,552 cwb bf16 frags (74KB)

__device__ __forceinline__ unsigned short f2bf(float f) {
    unsigned u = __float_as_uint(f);
    return (unsigned short)((u + 0x7FFFu + ((u >> 16) & 1u)) >> 16);
}

// value-only ascending top-2 (1 med3 + 1 max). s[0]=2nd largest, s[1]=largest.
__device__ __forceinline__ void insert2(float w, float (&s)[2]) {
    s[0] = __builtin_amdgcn_fmed3f(s[0], s[1], w);
    s[1] = fmaxf(s[1], w);
}

// θ = KTH-th largest of the union of the quad's 16 top-2 lists (destroys
// lists). Union ⊆ (row, half) values ⇒ θ ≤ half's KTH-th ≤ half's 9th
// (KTH=12 ≥ 9). Any row-global top-9 element in this half is within the
// half's top-9 ⇒ ≥ θ ⇒ collected in pass B. r14-proven.
__device__ __forceinline__ float popTheta2(float (&s)[2], int lane) {
    float theta = NEG_INF;
    #pragma unroll 1
    for (int p = 0; p < KTH; ++p) {
        float h = s[1];
        float m = h;
        m = fmaxf(m, __shfl_xor(m, 1));
        m = fmaxf(m, __shfl_xor(m, 2));
        m = fmaxf(m, __shfl_xor(m, 4));
        m = fmaxf(m, __shfl_xor(m, 8));
        unsigned long long bal = __ballot(h == m);
        unsigned qb = (unsigned)((bal >> (lane & 48)) & 0xFFFFull);
        int owner = __ffs(qb) - 1;
        if ((lane & 15) == owner) {
            s[1] = s[0]; s[0] = NEG_INF;
        }
        theta = m;
    }
    return theta;
}

// exact sorted-9 insert, value desc w/ index-asc tiebreak (final sort only)
__device__ __forceinline__ void insert9x(float w, int wi, float (&s)[9], int (&si)[9]) {
    bool c[9];
    #pragma unroll
    for (int k = 0; k < 9; ++k) c[k] = (w > s[k]) || (w == s[k] && wi < si[k]);
    #pragma unroll
    for (int k = 0; k < 8; ++k) si[k] = c[k + 1] ? si[k + 1] : (c[k] ? wi : si[k]);
    si[8] = c[8] ? wi : si[8];
    #pragma unroll
    for (int k = 0; k < 8; ++k) s[k] = c[k + 1] ? s[k + 1] : (c[k] ? w : s[k]);
    s[8] = c[8] ? w : s[8];
}

// ---------------------------------------------------------------------------
// K0: repack conv_w into bf16 MFMA B-FRAGMENT order:
//     cwb[((kk*4 + ot)*2 + ks)*64 + lane][i] = bf16(cw[o][cc*9 + kk])
//     with o = ot*16 + (lane&15), cc = ks*32 + (lane>>4)*8 + i.
// ---------------------------------------------------------------------------
__global__ void repack_cw_kernel(const float* __restrict__ cw, unsigned short* __restrict__ cwb) {
    int e = blockIdx.x * blockDim.x + threadIdx.x;      // (kk,ot,ks,lane)
    if (e >= KNN * 4 * 2 * 64) return;
    int lane = e & 63;
    int ks   = (e >> 6) & 1;
    int ot   = (e >> 7) & 3;
    int kk   = e >> 9;
    int o    = ot * 16 + (lane & 15);
    int cc0  = ks * 32 + (lane >> 4) * 8;
    unsigned short* dst = cwb + (size_t)e * 8;
    #pragma unroll
    for (int i = 0; i < 8; ++i)
        dst[i] = f2bf(cw[o * (CH * KNN) + (cc0 + i) * KNN + kk]);
}

// ---------------------------------------------------------------------------
// K1: QKV (fp32 VALU) + L2 normalize + q/k stores + u-projection on MFMA
//     (r15 win). q bf16 in MFMA B-fragment order (r9 win).
// ---------------------------------------------------------------------------
__global__ __launch_bounds__(256) void qkvu_kernel(
        const float* __restrict__ x,
        const float* __restrict__ Wq, const float* __restrict__ Wk, const float* __restrict__ Wv,
        const unsigned short* __restrict__ cwb,
        float* __restrict__ qtf, float* __restrict__ ktf,
        unsigned short* __restrict__ qtb, unsigned short* __restrict__ ktb,
        unsigned short* __restrict__ ub) {
    __shared__ __align__(16) float xs[CH * 64];
    __shared__ __align__(16) unsigned short vsb[64 * 64];   // v bf16, [t][cc]
    __shared__ float pq[4 * 64], pk[4 * 64];

    const int b   = blockIdx.x >> 6;
    const int tb  = blockIdx.x & 63;
    const int tid = threadIdx.x;

    const float* xb = x + ((size_t)b * CH) * TT + tb * 64;
    #pragma unroll
    for (int m = 0; m < 16; ++m) {
        int l = tid + 256 * m;
        xs[l] = xb[(size_t)(l >> 6) * TT + (l & 63)];
    }
    __syncthreads();

    const int t = tid & 63;
    const int g = __builtin_amdgcn_readfirstlane(tid >> 6);
    const int d0 = g * 16;

    float qa[16], ka[16], va[16];
    #pragma unroll
    for (int dd = 0; dd < 16; ++dd) { qa[dd] = 0.f; ka[dd] = 0.f; va[dd] = 0.f; }

    #pragma unroll 4
    for (int c = 0; c < CH; ++c) {
        float xv = xs[c * 64 + t];
        #pragma unroll
        for (int dd = 0; dd < 16; ++dd) {
            qa[dd] = fmaf(Wq[(d0 + dd) * CH + c], xv, qa[dd]);
            ka[dd] = fmaf(Wk[(d0 + dd) * CH + c], xv, ka[dd]);
            va[dd] = fmaf(Wv[(d0 + dd) * CH + c], xv, va[dd]);
        }
    }

    float sq = 0.f, sk = 0.f;
    #pragma unroll
    for (int dd = 0; dd < 16; ++dd) { sq = fmaf(qa[dd], qa[dd], sq); sk = fmaf(ka[dd], ka[dd], sk); }
    pq[g * 64 + t] = sq;
    pk[g * 64 + t] = sk;
    __syncthreads();

    const float nq = sqrtf(pq[t] + pq[64 + t] + pq[128 + t] + pq[192 + t]);
    const float nk = sqrtf(pk[t] + pk[64 + t] + pk[128 + t] + pk[192 + t]);
    const float isq = 1.0f / fmaxf(nq, 1e-12f);
    const float isk = 1.0f / fmaxf(nk, 1e-12f);

    const size_t tg = (size_t)tb * 64 + t;
    float qn[16], kn[16];
    #pragma unroll
    for (int dd = 0; dd < 16; ++dd) {
        qn[dd] = qa[dd] * isq;
        kn[dd] = ka[dd] * isk;
    }
    // v bf16 transposed [t][cc]: thread owns cc = d0..d0+15 of row t (32B contig)
    {
        unsigned* vh = (unsigned*)&vsb[t * 64 + d0];
        #pragma unroll
        for (int p = 0; p < 8; ++p)
            vh[p] = (unsigned)f2bf(va[2*p]) | ((unsigned)f2bf(va[2*p+1]) << 16);
    }
    float* qf = qtf + ((size_t)b * TT + tg) * CH + d0;
    float* kf = ktf + ((size_t)b * TT + tg) * CH + d0;
    #pragma unroll
    for (int p = 0; p < 4; ++p) {
        *(float4*)&qf[p * 4] = make_float4(qn[p*4], qn[p*4+1], qn[p*4+2], qn[p*4+3]);
        *(float4*)&kf[p * 4] = make_float4(kn[p*4], kn[p*4+1], kn[p*4+2], kn[p*4+3]);
    }
    // k bf16: row-major (A-fragments are only 4 loads/kernel in sim)
    unsigned* kh = (unsigned*)(ktb + ((size_t)b * TT + tg) * CH + d0);
    #pragma unroll
    for (int p = 0; p < 8; ++p)
        kh[p] = (unsigned)f2bf(kn[2*p]) | ((unsigned)f2bf(kn[2*p+1]) << 16);

    // q bf16: FRAGMENT order (see r9 comment)
    {
        const int j0   = (int)(tg >> 4);
        const int l15q = (int)tg & 15;
        const int ks   = g >> 1;
        const int q0   = (g & 1) * 2;
        #pragma unroll
        for (int h = 0; h < 2; ++h) {
            unsigned w0 = (unsigned)f2bf(qn[h*8+0]) | ((unsigned)f2bf(qn[h*8+1]) << 16);
            unsigned w1 = (unsigned)f2bf(qn[h*8+2]) | ((unsigned)f2bf(qn[h*8+3]) << 16);
            unsigned w2 = (unsigned)f2bf(qn[h*8+4]) | ((unsigned)f2bf(qn[h*8+5]) << 16);
            unsigned w3 = (unsigned)f2bf(qn[h*8+6]) | ((unsigned)f2bf(qn[h*8+7]) << 16);
            unsigned short* dst = qtb +
                ((((size_t)b * 256 + j0) * 2 + ks) * 64 + ((q0 + h) * 16 + l15q)) * 8;
            *(uint4*)dst = make_uint4(w0, w1, w2, w3);
        }
    }
    __syncthreads();

    // ---- u-projection via MFMA: u[t][o] = sum_cc v[t][cc] * cw[o][cc] ----
    const int l15 = t & 15;
    const int quad = t >> 4;
    s16x8 av[2];
    #pragma unroll
    for (int ks = 0; ks < 2; ++ks)
        av[ks] = *(const s16x8*)&vsb[(g * 16 + l15) * 64 + ks * 32 + quad * 8];

    #pragma unroll 1
    for (int kk = 0; kk < KNN; ++kk) {
        f32x4 ua[4];
        #pragma unroll
        for (int ot = 0; ot < 4; ++ot) ua[ot] = (f32x4){0.f, 0.f, 0.f, 0.f};
        #pragma unroll
        for (int ks = 0; ks < 2; ++ks)
            #pragma unroll
            for (int ot = 0; ot < 4; ++ot) {
                s16x8 bw = *(const s16x8*)(cwb + ((((size_t)kk * 4 + ot) * 2 + ks) * 64 + t) * 8);
                ua[ot] = __builtin_amdgcn_mfma_f32_16x16x32_bf16(av[ks], bw, ua[ot], 0, 0, 0);
            }
        const size_t rowb = (size_t)(b * KNN + kk) * TT + tb * 64 + g * 16 + quad * 4;
        #pragma unroll
        for (int ot = 0; ot < 4; ++ot)
            #pragma unroll
            for (int r = 0; r < 4; ++r)
                ub[(rowb + r) * CH + ot * 16 + l15] = f2bf(ua[ot][r]);
    }
}

// ---------------------------------------------------------------------------
// K2: FUSED sim + top-k + gather + conv (round-16).
//     Body = exact r14 sim (proven 135 µs). Tail change: instead of writing
//     idx to global for a separate gather kernel, the final top-9 indices go
//     to LDS (sidx) and THIS block performs the gather+conv for its own 64
//     t-rows (block (b,ib) owns exactly gather block (b,tb=ib)'s work; ub was
//     written by qkvu — no cross-block dependency). Removes a kernel launch,
//     the idx round-trip, and gather's standalone latency-bound wall time.
// ---------------------------------------------------------------------------
__global__ __launch_bounds__(256, 2) void sim_topk_kernel(
        const unsigned short* __restrict__ qtb, const unsigned short* __restrict__ ktb,
        const float* __restrict__ qtf, const float* __restrict__ ktf,
        const unsigned short* __restrict__ ub, const float* __restrict__ conv_b,
        float* __restrict__ out) {
    __shared__ int   cnt[64];
    __shared__ int   bkt[64 * SSTR];
    __shared__ float wbf[64 * SSTR];
    __shared__ int   sidx[64 * KNN];

    const int b    = blockIdx.x & 7;
    const int ib   = blockIdx.x >> 3;      // 0..63
    const int tid  = threadIdx.x;
    const int lane = tid & 63;
    const int w    = tid >> 6;             // wave 0..3
    const int w2r  = w >> 1;               // row half
    const int w2c  = w & 1;                // col half
    const int quad = lane >> 4;
    const int l15  = lane & 15;

    if (tid < 64) cnt[tid] = 0;
    __syncthreads();

    // k A-fragments in registers: rows w2r*32 + rt*16 + l15, k = quad*8+ks*32
    const unsigned short* kb = ktb + ((size_t)b * TT + ib * 64 + w2r * 32) * CH;
    s16x8 ka[2][2];
    #pragma unroll
    for (int rt = 0; rt < 2; ++rt)
        #pragma unroll
        for (int ks = 0; ks < 2; ++ks)
            ka[rt][ks] = *(const s16x8*)(kb + (size_t)(rt * 16 + l15) * CH + ks * 32 + quad * 8);

    // fragment-order q base for this batch & col-half:
    // frag[(b*256 + j0)*2 + ks][lane]*8, j0 = w2c*128 + jt*8 + jj
    const unsigned short* qfb = qtb + (((size_t)b * 256 + (size_t)w2c * 128) * 2) * 512
                                + (size_t)lane * 8;

    float s[2][4][2];
    #pragma unroll
    for (int rt = 0; rt < 2; ++rt)
        #pragma unroll
        for (int rg = 0; rg < 4; ++rg) { s[rt][rg][0] = NEG_INF; s[rt][rg][1] = NEG_INF; }

    // ------------------ PASS A: values-only top-2 (no barriers) ------------
    for (int jt = 0; jt < 16; ++jt) {
        const unsigned short* qrow = qfb + (size_t)(jt * 8) * 1024;  // j0 step=2*512
        s16x8 qf[8][2];
        #pragma unroll
        for (int jj = 0; jj < 8; ++jj)
            #pragma unroll
            for (int ks = 0; ks < 2; ++ks)
                qf[jj][ks] = *(const s16x8*)(qrow + (size_t)(jj * 2 + ks) * 512);

        f32x4 acc[2][8];
        #pragma unroll
        for (int rt = 0; rt < 2; ++rt)
            #pragma unroll
            for (int jj = 0; jj < 8; ++jj) acc[rt][jj] = (f32x4){0.f, 0.f, 0.f, 0.f};
        #pragma unroll
        for (int ks = 0; ks < 2; ++ks)
            #pragma unroll
            for (int rt = 0; rt < 2; ++rt)
                #pragma unroll
                for (int jj = 0; jj < 8; ++jj)
                    acc[rt][jj] = __builtin_amdgcn_mfma_f32_16x16x32_bf16(ka[rt][ks], qf[jj][ks], acc[rt][jj], 0, 0, 0);

        #pragma unroll
        for (int rt = 0; rt < 2; ++rt)
            #pragma unroll
            for (int jj = 0; jj < 8; ++jj) {
                insert2(acc[rt][jj][0], s[rt][0]);
                insert2(acc[rt][jj][1], s[rt][1]);
                insert2(acc[rt][jj][2], s[rt][2]);
                insert2(acc[rt][jj][3], s[rt][3]);
            }
    }

    // per-(row,half) θ — valid per half; no cross-wave merge needed
    float th[2][4];
    #pragma unroll
    for (int rt = 0; rt < 2; ++rt) {
        th[rt][0] = popTheta2(s[rt][0], lane);
        th[rt][1] = popTheta2(s[rt][1], lane);
        th[rt][2] = popTheta2(s[rt][2], lane);
        th[rt][3] = popTheta2(s[rt][3], lane);
    }

    // ------------------ PASS B: recompute (bitwise-identical) + collect ----
    for (int jt = 0; jt < 16; ++jt) {
        const unsigned short* qrow = qfb + (size_t)(jt * 8) * 1024;
        s16x8 qf[8][2];
        #pragma unroll
        for (int jj = 0; jj < 8; ++jj)
            #pragma unroll
            for (int ks = 0; ks < 2; ++ks)
                qf[jj][ks] = *(const s16x8*)(qrow + (size_t)(jj * 2 + ks) * 512);

        f32x4 acc[2][8];
        #pragma unroll
        for (int rt = 0; rt < 2; ++rt)
            #pragma unroll
            for (int jj = 0; jj < 8; ++jj) acc[rt][jj] = (f32x4){0.f, 0.f, 0.f, 0.f};
        #pragma unroll
        for (int ks = 0; ks < 2; ++ks)
            #pragma unroll
            for (int rt = 0; rt < 2; ++rt)
                #pragma unroll
                for (int jj = 0; jj < 8; ++jj)
                    acc[rt][jj] = __builtin_amdgcn_mfma_f32_16x16x32_bf16(ka[rt][ks], qf[jj][ks], acc[rt][jj], 0, 0, 0);

        #pragma unroll
        for (int rt = 0; rt < 2; ++rt)
            #pragma unroll
            for (int jj = 0; jj < 8; ++jj) {
                const int j = w2c * 2048 + jt * 128 + jj * 16 + l15;
                #pragma unroll
                for (int rg = 0; rg < 4; ++rg) {
                    if (acc[rt][jj][rg] >= th[rt][rg]) {
                        int rowl = w2r * 32 + rt * 16 + quad * 4 + rg;
                        int sl = atomicAdd(&cnt[rowl], 1);
                        if (sl < SLOTS) bkt[rowl * SSTR + sl] = j;
                    }
                }
            }
    }
    __syncthreads();

    // ------------------ exact fp32 rescore (L2-hot q/k fp32) ---------------
    {
        int r = tid >> 2, sub = tid & 3;
        int n = min(cnt[r], SLOTS);
        const float* krow = ktf + ((size_t)b * TT + ib * 64 + r) * CH;
        for (int m = sub; m < n; m += 4) {
            int j = bkt[r * SSTR + m];
            const float* qrow = qtf + ((size_t)b * TT + j) * CH;
            float wv = 0.f;
            #pragma unroll
            for (int c4 = 0; c4 < 16; ++c4) {
                float4 kv = *(const float4*)&krow[c4 * 4];
                float4 qv = *(const float4*)&qrow[c4 * 4];
                wv = fmaf(kv.x, qv.x, wv); wv = fmaf(kv.y, qv.y, wv);
                wv = fmaf(kv.z, qv.z, wv); wv = fmaf(kv.w, qv.w, wv);
            }
            wbf[r * SSTR + m] = wv;
        }
    }
    __syncthreads();

    if (tid < 64) {
        int n = min(cnt[tid], SLOTS);
        float s9[9]; int si9[9];
        #pragma unroll
        for (int k = 0; k < 9; ++k) { s9[k] = NEG_INF; si9[k] = 0x7fffffff; }
        #pragma unroll 1
        for (int m = 0; m < n; ++m) insert9x(wbf[tid * SSTR + m], bkt[tid * SSTR + m], s9, si9);
        #pragma unroll
        for (int m = 0; m < 9; ++m) sidx[tid * KNN + m] = si9[8 - m];
    }
    __syncthreads();

    // ------------------ fused gather + 1x1 conv (was gather_conv_kernel) ---
    {
        const int tl = tid & 63;
        const int og = tid >> 6;
        const int o0 = og * 16;

        float acc[16];
        #pragma unroll
        for (int q = 0; q < 16; ++q) acc[q] = conv_b[o0 + q];

        #pragma unroll
        for (int kk = 0; kk < KNN; ++kk) {
            int j = sidx[tl * KNN + kk];
            const unsigned short* up = ub + (((size_t)(b * KNN + kk)) * TT + j) * CH + o0;
            #pragma unroll
            for (int q8 = 0; q8 < 2; ++q8) {
                uint4 raw = *(const uint4*)&up[q8 * 8];
                unsigned rw[4] = {raw.x, raw.y, raw.z, raw.w};
                #pragma unroll
                for (int p = 0; p < 4; ++p) {
                    acc[q8 * 8 + 2 * p]     += __uint_as_float(rw[p] << 16);
                    acc[q8 * 8 + 2 * p + 1] += __uint_as_float(rw[p] & 0xFFFF0000u);
                }
            }
        }
        const int t = ib * 64 + tl;
        #pragma unroll
        for (int q = 0; q < 16; ++q)
            out[((size_t)b * CH + o0 + q) * TT + t] = acc[q];
    }
}

// ---------------------------------------------------------------------------
extern "C" void kernel_launch(void* const* d_in, const int* in_sizes, int n_in,
                              void* d_out, int out_size, void* d_ws, size_t ws_size,
                              hipStream_t stream) {
    const float* x   = (const float*)d_in[0];
    const float* Wq  = (const float*)d_in[1];
    const float* Wk  = (const float*)d_in[2];
    const float* Wv  = (const float*)d_in[3];
    const float* cw  = (const float*)d_in[4];
    const float* cbp = (const float*)d_in[5];

    float* ws = (float*)d_ws;
    unsigned short* ub  = (unsigned short*)(ws + OFF_UB);
    float* qtf          = ws + OFF_QTF;
    float* ktf          = ws + OFF_KTF;
    unsigned short* qtb = (unsigned short*)(ws + OFF_QTB);
    unsigned short* ktb = (unsigned short*)(ws + OFF_KTB);
    unsigned short* cwb = (unsigned short*)(ws + OFF_CWP);
    float* out          = (float*)d_out;

    repack_cw_kernel<<<(KNN * 4 * 2 * 64 + 255) / 256, 256, 0, stream>>>(cw, cwb);
    qkvu_kernel<<<BB * 64, 256, 0, stream>>>(x, Wq, Wk, Wv, cwb, qtf, ktf, qtb, ktb, ub);
    sim_topk_kernel<<<BB * 64, 256, 0, stream>>>(qtb, ktb, qtf, ktf, ub, cbp, out);
}

// Round 17
// 235.173 us; speedup vs baseline: 1.5249x; 1.0922x over previous
//
#include <hip/hip_runtime.h>
#include <hip/hip_bf16.h>
#include <cstdint>

// Problem constants
#define BB  8
#define CH  64
#define TT  4096
#define KNN 9
#define NEG_INF (-3.402823466e38f)
#define SLOTS 96          // candidate bucket per row (2 halves, insert2 θ looser)
#define SSTR  97          // padded LDS stride (odd -> conflict-free scans)
#define KTH   12          // θ = 12th largest of per-(row,half) lane-union

typedef short  s16x8 __attribute__((ext_vector_type(8)));   // 8 bf16 MFMA frag
typedef float  f32x4 __attribute__((ext_vector_type(4)));   // MFMA acc

// Workspace layout (float units) — end 16,060,416 floats = 64.2 MB
constexpr size_t OFF_UB  = 0;                                  // u bf16 [B][9][T][C] ushort
constexpr size_t OFF_QTF = (size_t)BB*KNN*TT*CH/2;             //  9,437,184 qhatT f32 [B][T][C]
constexpr size_t OFF_KTF = OFF_QTF + (size_t)BB*TT*CH;         // 11,534,336 khatT f32
constexpr size_t OFF_QTB = OFF_KTF + (size_t)BB*TT*CH;         // 13,631,488 q bf16 FRAGMENT order
constexpr size_t OFF_KTB = OFF_QTB + (size_t)BB*TT*CH/2;       // 14,680,064 khatT bf16 row-major
constexpr size_t OFF_IDX = OFF_KTB + (size_t)BB*TT*CH/2;       // 15,728,640 (unused since r16)
constexpr size_t OFF_CWP = OFF_IDX + (size_t)BB*TT*KNN;        // 16,023,552 cwb bf16 frags (74KB)

__device__ __forceinline__ unsigned short f2bf(float f) {
    unsigned u = __float_as_uint(f);
    return (unsigned short)((u + 0x7FFFu + ((u >> 16) & 1u)) >> 16);
}

// value-only ascending top-2 (1 med3 + 1 max). s[0]=2nd largest, s[1]=largest.
__device__ __forceinline__ void insert2(float w, float (&s)[2]) {
    s[0] = __builtin_amdgcn_fmed3f(s[0], s[1], w);
    s[1] = fmaxf(s[1], w);
}

// θ = KTH-th largest of the union of the quad's 16 top-2 lists (destroys
// lists). Union ⊆ (row, half) values ⇒ θ ≤ half's KTH-th ≤ half's 9th
// (KTH=12 ≥ 9). Any row-global top-9 element in this half is within the
// half's top-9 ⇒ ≥ θ ⇒ collected in pass B. r14-proven.
__device__ __forceinline__ float popTheta2(float (&s)[2], int lane) {
    float theta = NEG_INF;
    #pragma unroll 1
    for (int p = 0; p < KTH; ++p) {
        float h = s[1];
        float m = h;
        m = fmaxf(m, __shfl_xor(m, 1));
        m = fmaxf(m, __shfl_xor(m, 2));
        m = fmaxf(m, __shfl_xor(m, 4));
        m = fmaxf(m, __shfl_xor(m, 8));
        unsigned long long bal = __ballot(h == m);
        unsigned qb = (unsigned)((bal >> (lane & 48)) & 0xFFFFull);
        int owner = __ffs(qb) - 1;
        if ((lane & 15) == owner) {
            s[1] = s[0]; s[0] = NEG_INF;
        }
        theta = m;
    }
    return theta;
}

// exact sorted-9 insert, value desc w/ index-asc tiebreak (final sort only)
__device__ __forceinline__ void insert9x(float w, int wi, float (&s)[9], int (&si)[9]) {
    bool c[9];
    #pragma unroll
    for (int k = 0; k < 9; ++k) c[k] = (w > s[k]) || (w == s[k] && wi < si[k]);
    #pragma unroll
    for (int k = 0; k < 8; ++k) si[k] = c[k + 1] ? si[k + 1] : (c[k] ? wi : si[k]);
    si[8] = c[8] ? wi : si[8];
    #pragma unroll
    for (int k = 0; k < 8; ++k) s[k] = c[k + 1] ? s[k + 1] : (c[k] ? w : s[k]);
    s[8] = c[8] ? w : s[8];
}

// ---------------------------------------------------------------------------
// K0: repack conv_w into bf16 MFMA B-FRAGMENT order:
//     cwb[((kk*4 + ot)*2 + ks)*64 + lane][i] = bf16(cw[o][cc*9 + kk])
//     with o = ot*16 + (lane&15), cc = ks*32 + (lane>>4)*8 + i.
// ---------------------------------------------------------------------------
__global__ void repack_cw_kernel(const float* __restrict__ cw, unsigned short* __restrict__ cwb) {
    int e = blockIdx.x * blockDim.x + threadIdx.x;      // (kk,ot,ks,lane)
    if (e >= KNN * 4 * 2 * 64) return;
    int lane = e & 63;
    int ks   = (e >> 6) & 1;
    int ot   = (e >> 7) & 3;
    int kk   = e >> 9;
    int o    = ot * 16 + (lane & 15);
    int cc0  = ks * 32 + (lane >> 4) * 8;
    unsigned short* dst = cwb + (size_t)e * 8;
    #pragma unroll
    for (int i = 0; i < 8; ++i)
        dst[i] = f2bf(cw[o * (CH * KNN) + (cc0 + i) * KNN + kk]);
}

// ---------------------------------------------------------------------------
// K1: QKV (fp32 VALU) + L2 normalize + q/k stores + u-projection on MFMA.
//     Round-17: *** 512 threads / 8 waves, d-split 8 ***. Wave g owns dims
//     g*8..+7: per-wave serial path halves, waves/SIMD 2->4 (qkvu is
//     latency-bound on uniform weight loads + stores). Register footprint
//     ~64 VGPR — far below any cap, no r10-style spill risk. Norm reduction
//     over 8 partials. qtb fragment store: thread's 8 dims = exactly chunk
//     (ks=g>>2, quad=g&3) -> ONE uint4. u-proj: wave g -> row-tile (g&3),
//     ot-pair (g>>2): 36 MFMA/wave (same 288/block total).
// ---------------------------------------------------------------------------
__global__ __launch_bounds__(512) void qkvu_kernel(
        const float* __restrict__ x,
        const float* __restrict__ Wq, const float* __restrict__ Wk, const float* __restrict__ Wv,
        const unsigned short* __restrict__ cwb,
        float* __restrict__ qtf, float* __restrict__ ktf,
        unsigned short* __restrict__ qtb, unsigned short* __restrict__ ktb,
        unsigned short* __restrict__ ub) {
    __shared__ __align__(16) float xs[CH * 64];
    __shared__ __align__(16) unsigned short vsb[64 * 64];   // v bf16, [t][cc]
    __shared__ float pq[8 * 64], pk[8 * 64];

    const int b   = blockIdx.x >> 6;
    const int tb  = blockIdx.x & 63;
    const int tid = threadIdx.x;

    const float* xb = x + ((size_t)b * CH) * TT + tb * 64;
    #pragma unroll
    for (int m = 0; m < 8; ++m) {
        int l = tid + 512 * m;
        xs[l] = xb[(size_t)(l >> 6) * TT + (l & 63)];
    }
    __syncthreads();

    const int t = tid & 63;
    const int g = __builtin_amdgcn_readfirstlane(tid >> 6);   // 0..7
    const int d0 = g * 8;

    float qa[8], ka[8], va[8];
    #pragma unroll
    for (int dd = 0; dd < 8; ++dd) { qa[dd] = 0.f; ka[dd] = 0.f; va[dd] = 0.f; }

    #pragma unroll 4
    for (int c = 0; c < CH; ++c) {
        float xv = xs[c * 64 + t];
        #pragma unroll
        for (int dd = 0; dd < 8; ++dd) {
            qa[dd] = fmaf(Wq[(d0 + dd) * CH + c], xv, qa[dd]);
            ka[dd] = fmaf(Wk[(d0 + dd) * CH + c], xv, ka[dd]);
            va[dd] = fmaf(Wv[(d0 + dd) * CH + c], xv, va[dd]);
        }
    }

    float sq = 0.f, sk = 0.f;
    #pragma unroll
    for (int dd = 0; dd < 8; ++dd) { sq = fmaf(qa[dd], qa[dd], sq); sk = fmaf(ka[dd], ka[dd], sk); }
    pq[g * 64 + t] = sq;
    pk[g * 64 + t] = sk;
    __syncthreads();

    float nq2 = 0.f, nk2 = 0.f;
    #pragma unroll
    for (int p = 0; p < 8; ++p) { nq2 += pq[p * 64 + t]; nk2 += pk[p * 64 + t]; }
    const float isq = 1.0f / fmaxf(sqrtf(nq2), 1e-12f);
    const float isk = 1.0f / fmaxf(sqrtf(nk2), 1e-12f);

    const size_t tg = (size_t)tb * 64 + t;
    float qn[8], kn[8];
    #pragma unroll
    for (int dd = 0; dd < 8; ++dd) {
        qn[dd] = qa[dd] * isq;
        kn[dd] = ka[dd] * isk;
    }
    // v bf16 transposed [t][cc]: thread owns cc = d0..d0+7 of row t (16B contig)
    {
        unsigned* vh = (unsigned*)&vsb[t * 64 + d0];
        #pragma unroll
        for (int p = 0; p < 4; ++p)
            vh[p] = (unsigned)f2bf(va[2*p]) | ((unsigned)f2bf(va[2*p+1]) << 16);
    }
    float* qf = qtf + ((size_t)b * TT + tg) * CH + d0;
    float* kf = ktf + ((size_t)b * TT + tg) * CH + d0;
    #pragma unroll
    for (int p = 0; p < 2; ++p) {
        *(float4*)&qf[p * 4] = make_float4(qn[p*4], qn[p*4+1], qn[p*4+2], qn[p*4+3]);
        *(float4*)&kf[p * 4] = make_float4(kn[p*4], kn[p*4+1], kn[p*4+2], kn[p*4+3]);
    }
    // k bf16: row-major
    {
        unsigned* kh = (unsigned*)(ktb + ((size_t)b * TT + tg) * CH + d0);
        #pragma unroll
        for (int p = 0; p < 4; ++p)
            kh[p] = (unsigned)f2bf(kn[2*p]) | ((unsigned)f2bf(kn[2*p+1]) << 16);
    }
    // q bf16: FRAGMENT order — thread's 8 dims = chunk (ks = g>>2, quad = g&3)
    {
        const int j0   = (int)(tg >> 4);
        const int l15q = (int)tg & 15;
        const int ks   = g >> 2;
        const int qd   = g & 3;
        unsigned w0 = (unsigned)f2bf(qn[0]) | ((unsigned)f2bf(qn[1]) << 16);
        unsigned w1 = (unsigned)f2bf(qn[2]) | ((unsigned)f2bf(qn[3]) << 16);
        unsigned w2 = (unsigned)f2bf(qn[4]) | ((unsigned)f2bf(qn[5]) << 16);
        unsigned w3 = (unsigned)f2bf(qn[6]) | ((unsigned)f2bf(qn[7]) << 16);
        unsigned short* dst = qtb +
            ((((size_t)b * 256 + j0) * 2 + ks) * 64 + (qd * 16 + l15q)) * 8;
        *(uint4*)dst = make_uint4(w0, w1, w2, w3);
    }
    __syncthreads();

    // ---- u-projection via MFMA: u[t][o] = sum_cc v[t][cc] * cw[o][cc] ----
    // Wave g: row-tile rt4 = g&3 (t-rows rt4*16..+15), ot-pair oth = g>>2.
    const int l15 = t & 15;
    const int quad = t >> 4;
    const int rt4 = g & 3;
    const int oth = g >> 2;
    s16x8 av[2];
    #pragma unroll
    for (int ks = 0; ks < 2; ++ks)
        av[ks] = *(const s16x8*)&vsb[(rt4 * 16 + l15) * 64 + ks * 32 + quad * 8];

    #pragma unroll 1
    for (int kk = 0; kk < KNN; ++kk) {
        f32x4 ua[2];
        ua[0] = (f32x4){0.f, 0.f, 0.f, 0.f};
        ua[1] = (f32x4){0.f, 0.f, 0.f, 0.f};
        #pragma unroll
        for (int ks = 0; ks < 2; ++ks)
            #pragma unroll
            for (int oi = 0; oi < 2; ++oi) {
                const int ot = oth * 2 + oi;
                s16x8 bw = *(const s16x8*)(cwb + ((((size_t)kk * 4 + ot) * 2 + ks) * 64 + t) * 8);
                ua[oi] = __builtin_amdgcn_mfma_f32_16x16x32_bf16(av[ks], bw, ua[oi], 0, 0, 0);
            }
        const size_t rowb = (size_t)(b * KNN + kk) * TT + tb * 64 + rt4 * 16 + quad * 4;
        #pragma unroll
        for (int oi = 0; oi < 2; ++oi)
            #pragma unroll
            for (int r = 0; r < 4; ++r)
                ub[(rowb + r) * CH + (oth * 2 + oi) * 16 + l15] = f2bf(ua[oi][r]);
    }
}

// ---------------------------------------------------------------------------
// K2: FUSED sim + top-k + gather + conv (r16 win, untouched this round).
// ---------------------------------------------------------------------------
__global__ __launch_bounds__(256, 2) void sim_topk_kernel(
        const unsigned short* __restrict__ qtb, const unsigned short* __restrict__ ktb,
        const float* __restrict__ qtf, const float* __restrict__ ktf,
        const unsigned short* __restrict__ ub, const float* __restrict__ conv_b,
        float* __restrict__ out) {
    __shared__ int   cnt[64];
    __shared__ int   bkt[64 * SSTR];
    __shared__ float wbf[64 * SSTR];
    __shared__ int   sidx[64 * KNN];

    const int b    = blockIdx.x & 7;
    const int ib   = blockIdx.x >> 3;      // 0..63
    const int tid  = threadIdx.x;
    const int lane = tid & 63;
    const int w    = tid >> 6;             // wave 0..3
    const int w2r  = w >> 1;               // row half
    const int w2c  = w & 1;                // col half
    const int quad = lane >> 4;
    const int l15  = lane & 15;

    if (tid < 64) cnt[tid] = 0;
    __syncthreads();

    // k A-fragments in registers: rows w2r*32 + rt*16 + l15, k = quad*8+ks*32
    const unsigned short* kb = ktb + ((size_t)b * TT + ib * 64 + w2r * 32) * CH;
    s16x8 ka[2][2];
    #pragma unroll
    for (int rt = 0; rt < 2; ++rt)
        #pragma unroll
        for (int ks = 0; ks < 2; ++ks)
            ka[rt][ks] = *(const s16x8*)(kb + (size_t)(rt * 16 + l15) * CH + ks * 32 + quad * 8);

    // fragment-order q base for this batch & col-half:
    // frag[(b*256 + j0)*2 + ks][lane]*8, j0 = w2c*128 + jt*8 + jj
    const unsigned short* qfb = qtb + (((size_t)b * 256 + (size_t)w2c * 128) * 2) * 512
                                + (size_t)lane * 8;

    float s[2][4][2];
    #pragma unroll
    for (int rt = 0; rt < 2; ++rt)
        #pragma unroll
        for (int rg = 0; rg < 4; ++rg) { s[rt][rg][0] = NEG_INF; s[rt][rg][1] = NEG_INF; }

    // ------------------ PASS A: values-only top-2 (no barriers) ------------
    for (int jt = 0; jt < 16; ++jt) {
        const unsigned short* qrow = qfb + (size_t)(jt * 8) * 1024;  // j0 step=2*512
        s16x8 qf[8][2];
        #pragma unroll
        for (int jj = 0; jj < 8; ++jj)
            #pragma unroll
            for (int ks = 0; ks < 2; ++ks)
                qf[jj][ks] = *(const s16x8*)(qrow + (size_t)(jj * 2 + ks) * 512);

        f32x4 acc[2][8];
        #pragma unroll
        for (int rt = 0; rt < 2; ++rt)
            #pragma unroll
            for (int jj = 0; jj < 8; ++jj) acc[rt][jj] = (f32x4){0.f, 0.f, 0.f, 0.f};
        #pragma unroll
        for (int ks = 0; ks < 2; ++ks)
            #pragma unroll
            for (int rt = 0; rt < 2; ++rt)
                #pragma unroll
                for (int jj = 0; jj < 8; ++jj)
                    acc[rt][jj] = __builtin_amdgcn_mfma_f32_16x16x32_bf16(ka[rt][ks], qf[jj][ks], acc[rt][jj], 0, 0, 0);

        #pragma unroll
        for (int rt = 0; rt < 2; ++rt)
            #pragma unroll
            for (int jj = 0; jj < 8; ++jj) {
                insert2(acc[rt][jj][0], s[rt][0]);
                insert2(acc[rt][jj][1], s[rt][1]);
                insert2(acc[rt][jj][2], s[rt][2]);
                insert2(acc[rt][jj][3], s[rt][3]);
            }
    }

    // per-(row,half) θ — valid per half; no cross-wave merge needed
    float th[2][4];
    #pragma unroll
    for (int rt = 0; rt < 2; ++rt) {
        th[rt][0] = popTheta2(s[rt][0], lane);
        th[rt][1] = popTheta2(s[rt][1], lane);
        th[rt][2] = popTheta2(s[rt][2], lane);
        th[rt][3] = popTheta2(s[rt][3], lane);
    }

    // ------------------ PASS B: recompute (bitwise-identical) + collect ----
    for (int jt = 0; jt < 16; ++jt) {
        const unsigned short* qrow = qfb + (size_t)(jt * 8) * 1024;
        s16x8 qf[8][2];
        #pragma unroll
        for (int jj = 0; jj < 8; ++jj)
            #pragma unroll
            for (int ks = 0; ks < 2; ++ks)
                qf[jj][ks] = *(const s16x8*)(qrow + (size_t)(jj * 2 + ks) * 512);

        f32x4 acc[2][8];
        #pragma unroll
        for (int rt = 0; rt < 2; ++rt)
            #pragma unroll
            for (int jj = 0; jj < 8; ++jj) acc[rt][jj] = (f32x4){0.f, 0.f, 0.f, 0.f};
        #pragma unroll
        for (int ks = 0; ks < 2; ++ks)
            #pragma unroll
            for (int rt = 0; rt < 2; ++rt)
                #pragma unroll
                for (int jj = 0; jj < 8; ++jj)
                    acc[rt][jj] = __builtin_amdgcn_mfma_f32_16x16x32_bf16(ka[rt][ks], qf[jj][ks], acc[rt][jj], 0, 0, 0);

        #pragma unroll
        for (int rt = 0; rt < 2; ++rt)
            #pragma unroll
            for (int jj = 0; jj < 8; ++jj) {
                const int j = w2c * 2048 + jt * 128 + jj * 16 + l15;
                #pragma unroll
                for (int rg = 0; rg < 4; ++rg) {
                    if (acc[rt][jj][rg] >= th[rt][rg]) {
                        int rowl = w2r * 32 + rt * 16 + quad * 4 + rg;
                        int sl = atomicAdd(&cnt[rowl], 1);
                        if (sl < SLOTS) bkt[rowl * SSTR + sl] = j;
                    }
                }
            }
    }
    __syncthreads();

    // ------------------ exact fp32 rescore (L2-hot q/k fp32) ---------------
    {
        int r = tid >> 2, sub = tid & 3;
        int n = min(cnt[r], SLOTS);
        const float* krow = ktf + ((size_t)b * TT + ib * 64 + r) * CH;
        for (int m = sub; m < n; m += 4) {
            int j = bkt[r * SSTR + m];
            const float* qrow = qtf + ((size_t)b * TT + j) * CH;
            float wv = 0.f;
            #pragma unroll
            for (int c4 = 0; c4 < 16; ++c4) {
                float4 kv = *(const float4*)&krow[c4 * 4];
                float4 qv = *(const float4*)&qrow[c4 * 4];
                wv = fmaf(kv.x, qv.x, wv); wv = fmaf(kv.y, qv.y, wv);
                wv = fmaf(kv.z, qv.z, wv); wv = fmaf(kv.w, qv.w, wv);
            }
            wbf[r * SSTR + m] = wv;
        }
    }
    __syncthreads();

    if (tid < 64) {
        int n = min(cnt[tid], SLOTS);
        float s9[9]; int si9[9];
        #pragma unroll
        for (int k = 0; k < 9; ++k) { s9[k] = NEG_INF; si9[k] = 0x7fffffff; }
        #pragma unroll 1
        for (int m = 0; m < n; ++m) insert9x(wbf[tid * SSTR + m], bkt[tid * SSTR + m], s9, si9);
        #pragma unroll
        for (int m = 0; m < 9; ++m) sidx[tid * KNN + m] = si9[8 - m];
    }
    __syncthreads();

    // ------------------ fused gather + 1x1 conv ----------------------------
    {
        const int tl = tid & 63;
        const int og = tid >> 6;
        const int o0 = og * 16;

        float acc[16];
        #pragma unroll
        for (int q = 0; q < 16; ++q) acc[q] = conv_b[o0 + q];

        #pragma unroll
        for (int kk = 0; kk < KNN; ++kk) {
            int j = sidx[tl * KNN + kk];
            const unsigned short* up = ub + (((size_t)(b * KNN + kk)) * TT + j) * CH + o0;
            #pragma unroll
            for (int q8 = 0; q8 < 2; ++q8) {
                uint4 raw = *(const uint4*)&up[q8 * 8];
                unsigned rw[4] = {raw.x, raw.y, raw.z, raw.w};
                #pragma unroll
                for (int p = 0; p < 4; ++p) {
                    acc[q8 * 8 + 2 * p]     += __uint_as_float(rw[p] << 16);
                    acc[q8 * 8 + 2 * p + 1] += __uint_as_float(rw[p] & 0xFFFF0000u);
                }
            }
        }
        const int t = ib * 64 + tl;
        #pragma unroll
        for (int q = 0; q < 16; ++q)
            out[((size_t)b * CH + o0 + q) * TT + t] = acc[q];
    }
}

// ---------------------------------------------------------------------------
extern "C" void kernel_launch(void* const* d_in, const int* in_sizes, int n_in,
                              void* d_out, int out_size, void* d_ws, size_t ws_size,
                              hipStream_t stream) {
    const float* x   = (const float*)d_in[0];
    const float* Wq  = (const float*)d_in[1];
    const float* Wk  = (const float*)d_in[2];
    const float* Wv  = (const float*)d_in[3];
    const float* cw  = (const float*)d_in[4];
    const float* cbp = (const float*)d_in[5];

    float* ws = (float*)d_ws;
    unsigned short* ub  = (unsigned short*)(ws + OFF_UB);
    float* qtf          = ws + OFF_QTF;
    float* ktf          = ws + OFF_KTF;
    unsigned short* qtb = (unsigned short*)(ws + OFF_QTB);
    unsigned short* ktb = (unsigned short*)(ws + OFF_KTB);
    unsigned short* cwb = (unsigned short*)(ws + OFF_CWP);
    float* out          = (float*)d_out;

    repack_cw_kernel<<<(KNN * 4 * 2 * 64 + 255) / 256, 256, 0, stream>>>(cw, cwb);
    qkvu_kernel<<<BB * 64, 512, 0, stream>>>(x, Wq, Wk, Wv, cwb, qtf, ktf, qtb, ktb, ub);
    sim_topk_kernel<<<BB * 64, 256, 0, stream>>>(qtb, ktb, qtf, ktf, ub, cbp, out);
}